// Round 1
// baseline (12851.349 us; speedup 1.0000x reference)
//
#include <hip/hip_runtime.h>
#include <math.h>

// Problem constants
#define Bn   2
#define Tn   2048
#define Cdim 1024
#define HSn  64
#define En   8
#define NRn  6
#define Pn   4
#define Hn   16            // C/HS
#define FFn  4096          // 4*C
#define NTn  2
#define BTn  4096          // B*T

// ---------------- LayerNorm ----------------
__global__ __launch_bounds__(256) void ln_kernel(const float* __restrict__ x,
                                                 const float* __restrict__ w,
                                                 const float* __restrict__ b,
                                                 float* __restrict__ out) {
    int row = blockIdx.x;
    const float* xr = x + (size_t)row * Cdim;
    float s = 0.f, s2 = 0.f;
    for (int c = threadIdx.x; c < Cdim; c += 256) {
        float v = xr[c];
        s += v; s2 += v * v;
    }
    __shared__ float rs[256], rs2[256];
    rs[threadIdx.x] = s; rs2[threadIdx.x] = s2;
    __syncthreads();
    for (int st = 128; st > 0; st >>= 1) {
        if (threadIdx.x < st) {
            rs[threadIdx.x]  += rs[threadIdx.x + st];
            rs2[threadIdx.x] += rs2[threadIdx.x + st];
        }
        __syncthreads();
    }
    float mean = rs[0] / Cdim;
    float var  = rs2[0] / Cdim - mean * mean;
    float inv  = rsqrtf(var + 1e-5f);
    float* orow = out + (size_t)row * Cdim;
    for (int c = threadIdx.x; c < Cdim; c += 256)
        orow[c] = (xr[c] - mean) * inv * w[c] + b[c];
}

// ---------------- Tiled fp32 GEMM with epilogues ----------------
// C(M,N) = A(M,K) @ B(K,N), row-major. 128x128 tile, BK=8, 256 thr, 8x8/thr.
enum { EP_NONE = 0, EP_ADD = 1, EP_SIGB = 2, EP_RELU2 = 3, EP_TANH = 4, EP_SIG = 5, EP_MOE = 6 };

template <int EP>
__global__ __launch_bounds__(256) void gemm_kernel(
    const float* __restrict__ A, const float* __restrict__ B, float* __restrict__ C,
    int M, int N, int K,
    const float* __restrict__ aux1,   // EP_ADD: residual (M,N); EP_SIGB: bias (N); EP_MOE: gate base (stride gstride)
    const float* __restrict__ aux2,   // EP_MOE: elementwise multiplier (M,N) or null
    int gstride) {
    __shared__ float As[8][128];
    __shared__ float Bs[8][128];
    int tid = threadIdx.x;
    int tx = tid & 15, ty = tid >> 4;
    int m0 = blockIdx.y * 128, n0 = blockIdx.x * 128;

    float acc[8][8];
#pragma unroll
    for (int i = 0; i < 8; i++)
#pragma unroll
        for (int j = 0; j < 8; j++) acc[i][j] = 0.f;

    int aRow = tid >> 1;          // 0..127
    int aCol = (tid & 1) * 4;     // 0 or 4
    int bRow = tid >> 5;          // 0..7
    int bCol = (tid & 31) * 4;    // 0..124
    const float* Aptr = A + (size_t)(m0 + aRow) * K + aCol;
    const float* Bptr = B + (size_t)bRow * N + n0 + bCol;

    for (int kt = 0; kt < K; kt += 8) {
        float4 a4 = *(const float4*)(Aptr + kt);
        float4 b4 = *(const float4*)(Bptr + (size_t)kt * N);
        As[aCol + 0][aRow] = a4.x;
        As[aCol + 1][aRow] = a4.y;
        As[aCol + 2][aRow] = a4.z;
        As[aCol + 3][aRow] = a4.w;
        *(float4*)&Bs[bRow][bCol] = b4;
        __syncthreads();
#pragma unroll
        for (int k = 0; k < 8; k++) {
            float4 a0 = *(const float4*)&As[k][ty * 8];
            float4 a1 = *(const float4*)&As[k][ty * 8 + 4];
            float4 b0 = *(const float4*)&Bs[k][tx * 8];
            float4 b1 = *(const float4*)&Bs[k][tx * 8 + 4];
            float av[8] = {a0.x, a0.y, a0.z, a0.w, a1.x, a1.y, a1.z, a1.w};
            float bv[8] = {b0.x, b0.y, b0.z, b0.w, b1.x, b1.y, b1.z, b1.w};
#pragma unroll
            for (int i = 0; i < 8; i++)
#pragma unroll
                for (int j = 0; j < 8; j++) acc[i][j] += av[i] * bv[j];
        }
        __syncthreads();
    }

#pragma unroll
    for (int i = 0; i < 8; i++) {
        int gm = m0 + ty * 8 + i;
        float g = 0.f;
        if (EP == EP_MOE) g = aux1[(size_t)gm * gstride];
#pragma unroll
        for (int j = 0; j < 8; j++) {
            int gn = n0 + tx * 8 + j;
            size_t idx = (size_t)gm * N + gn;
            float v = acc[i][j];
            if (EP == EP_NONE) {
                C[idx] = v;
            } else if (EP == EP_ADD) {
                C[idx] = aux1[idx] + v;
            } else if (EP == EP_SIGB) {
                C[idx] = 1.f / (1.f + expf(-(v + aux1[gn])));
            } else if (EP == EP_RELU2) {
                float r = fmaxf(v, 0.f);
                C[idx] = r * r;
            } else if (EP == EP_TANH) {
                C[idx] = tanhf(v);
            } else if (EP == EP_SIG) {
                C[idx] = 1.f / (1.f + expf(-v));
            } else if (EP == EP_MOE) {
                float m = aux2 ? aux2[idx] : 1.f;
                C[idx] += g * m * v;
            }
        }
    }
}

// ---------------- RWKV7 per-head scan ----------------
// One block per (b,h). 256 threads: lane j = tid&63 (v index), group ig = tid>>6 owns rows ig*16..+15.
__global__ __launch_bounds__(256) void rwkv_scan_kernel(
    const float* __restrict__ r, const float* __restrict__ k,
    const float* __restrict__ v, const float* __restrict__ w,
    float* __restrict__ y) {
    int bh = blockIdx.x;
    int b = bh / Hn, h = bh % Hn;
    int tid = threadIdx.x;
    int j = tid & 63;
    int ig = tid >> 6;
    __shared__ float sr[64], sk[64], sv[64], sw[64];
    __shared__ float red[4][64];
    float S[16];
#pragma unroll
    for (int i = 0; i < 16; i++) S[i] = 0.f;

    size_t base = (size_t)b * Tn * Cdim + (size_t)h * HSn;
    const float* srcs[4] = {r, k, v, w};
    const float* myp = srcs[ig] + base + j;
    float cur = myp[0];

    for (int t = 0; t < Tn; t++) {
        float* dst = (ig == 0 ? sr : ig == 1 ? sk : ig == 2 ? sv : sw);
        dst[j] = cur;
        __syncthreads();
        float nxt = (t + 1 < Tn) ? myp[(size_t)(t + 1) * Cdim] : 0.f;
        float vj = sv[j];
        float part = 0.f;
#pragma unroll
        for (int ii = 0; ii < 16; ii++) {
            int i = ig * 16 + ii;
            S[ii] = S[ii] * sw[i] + sk[i] * vj;
            part += sr[i] * S[ii];
        }
        red[ig][j] = part;
        __syncthreads();
        if (ig == 0) {
            y[((size_t)b * Tn + t) * Cdim + (size_t)h * HSn + j] =
                red[0][j] + red[1][j] + red[2][j] + red[3][j];
        }
        cur = nxt;
    }
}

// ---------------- Routing: conf, subsidy softmax, top-2, gates ----------------
__global__ __launch_bounds__(256) void routing_kernel(
    const float* __restrict__ h, const float* __restrict__ conf_w,
    const float* __restrict__ conf_b, const float* __restrict__ Wa,
    const float* __restrict__ ba, const float* __restrict__ cap,
    float* __restrict__ gates) {
    int row = blockIdx.x;
    const float* hr = h + (size_t)row * Cdim;
    float pc[8], pa[8];
#pragma unroll
    for (int e = 0; e < 8; e++) { pc[e] = 0.f; pa[e] = 0.f; }
    for (int c = threadIdx.x; c < Cdim; c += 256) {
        float hv = hr[c];
#pragma unroll
        for (int e = 0; e < 8; e++) {
            pc[e] += hv * conf_w[(size_t)e * Cdim + c];
            pa[e] += hv * Wa[(size_t)c * En + e];
        }
    }
    __shared__ float red[256];
    __shared__ float vals[16];
    for (int e = 0; e < 16; e++) {
        red[threadIdx.x] = (e < 8) ? pc[e] : pa[e - 8];
        __syncthreads();
        for (int st = 128; st > 0; st >>= 1) {
            if (threadIdx.x < st) red[threadIdx.x] += red[threadIdx.x + st];
            __syncthreads();
        }
        if (threadIdx.x == 0) vals[e] = red[0];
        __syncthreads();
    }
    if (threadIdx.x == 0) {
        float conf[8], aff[8];
        for (int e = 0; e < 8; e++) {
            conf[e] = 1.f / (1.f + expf(-(vals[e] + conf_b[e])));
            aff[e]  = vals[8 + e] + ba[e];
        }
        float mx = aff[0];
        for (int e = 1; e < 8; e++) mx = fmaxf(mx, aff[e]);
        float se = 0.f, ex[8];
        for (int e = 0; e < 8; e++) { ex[e] = expf(aff[e] - mx); se += ex[e]; }
        float bids[8];
        for (int e = 0; e < 8; e++) bids[e] = conf[e] * cap[e] + ex[e] / se;
        int w0 = 0;
        for (int e = 1; e < 8; e++) if (bids[e] > bids[w0]) w0 = e;
        int w1 = -1;
        for (int e = 0; e < 8; e++) {
            if (e == w0) continue;
            if (w1 < 0 || bids[e] > bids[w1]) w1 = e;
        }
        float e1 = expf(bids[w1] - bids[w0]);  // v1 <= v0, stable
        float g0 = 1.f / (1.f + e1);
        float g1 = e1 / (1.f + e1);
        float* g = gates + (size_t)row * En;
        for (int e = 0; e < 8; e++) g[e] = 0.f;
        g[w0] = g0;
        g[w1] = g1;
    }
}

// ---------------- concat [h, state] -> (BT, 2C) ----------------
__global__ __launch_bounds__(256) void concat_kernel(const float* __restrict__ h,
                                                     const float* __restrict__ st,
                                                     float* __restrict__ hs) {
    size_t i = (size_t)blockIdx.x * 256 + threadIdx.x;  // over BT*C
    size_t row = i / Cdim, c = i % Cdim;
    hs[row * (2 * Cdim) + c] = h[i];
    hs[row * (2 * Cdim) + Cdim + c] = st[i];
}

// ---------------- transformer-expert prefix attention ----------------
// one wave per (token n, head h): P=4 keys/values of dim 64
__global__ __launch_bounds__(256) void tr_attn_kernel(
    const float* __restrict__ q, const float* __restrict__ kp,
    const float* __restrict__ vp, float* __restrict__ out) {
    int idx = blockIdx.x * 4 + (threadIdx.x >> 6);  // n*H + h
    int lane = threadIdx.x & 63;
    int n = idx / Hn, h = idx % Hn;
    const float* qv = q + (size_t)n * Cdim + (size_t)h * HSn;
    float qd = qv[lane];
    float s[4];
#pragma unroll
    for (int p = 0; p < 4; p++) {
        const float* kv = kp + ((size_t)n * Pn + p) * Cdim + (size_t)h * HSn;
        float t = qd * kv[lane];
        for (int off = 32; off > 0; off >>= 1) t += __shfl_down(t, off);
        s[p] = __shfl(t, 0);
    }
    const float scale = 0.125f;  // 1/sqrt(64)
    float mx = fmaxf(fmaxf(s[0], s[1]), fmaxf(s[2], s[3])) * scale;
    float es = 0.f, a[4];
#pragma unroll
    for (int p = 0; p < 4; p++) { a[p] = expf(s[p] * scale - mx); es += a[p]; }
    float o = 0.f;
#pragma unroll
    for (int p = 0; p < 4; p++) {
        const float* vv = vp + ((size_t)n * Pn + p) * Cdim + (size_t)h * HSn;
        o += (a[p] / es) * vv[lane];
    }
    out[(size_t)n * Cdim + (size_t)h * HSn + lane] = o;
}

// ---------------- orchestration ----------------
extern "C" void kernel_launch(void* const* d_in, const int* in_sizes, int n_in,
                              void* d_out, int out_size, void* d_ws, size_t ws_size,
                              hipStream_t stream) {
    const float* x      = (const float*)d_in[0];
    const float* cap    = (const float*)d_in[2];
    const float* ln1_w  = (const float*)d_in[3];
    const float* ln1_b  = (const float*)d_in[4];
    const float* ln2_w  = (const float*)d_in[5];
    const float* ln2_b  = (const float*)d_in[6];
    const float* Wr     = (const float*)d_in[7];
    const float* Wk     = (const float*)d_in[8];
    const float* Wv     = (const float*)d_in[9];
    const float* Ww     = (const float*)d_in[10];
    const float* w_bias = (const float*)d_in[11];
    const float* Wo     = (const float*)d_in[12];
    const float* conf_w = (const float*)d_in[13];
    const float* conf_b = (const float*)d_in[14];
    const float* Wa     = (const float*)d_in[17];
    const float* ba     = (const float*)d_in[18];
    const float* Wb     = (const float*)d_in[19];
    const float* ffn_Wr = (const float*)d_in[20];
    const float* ffn_Wk = (const float*)d_in[21];
    const float* ffn_Wv = (const float*)d_in[22];
    const float* tr_Wq  = (const float*)d_in[23];
    const float* tr_Wk  = (const float*)d_in[24];
    const float* tr_Wv  = (const float*)d_in[25];
    const float* tr_Wo  = (const float*)d_in[26];

    float* xout  = (float*)d_out;                       // x_after_att, then += gated experts
    float* vflat = (float*)d_out + (size_t)BTn * Cdim;  // v_flat output

    char* ws = (char*)d_ws;
    const size_t MB = 1ull << 20;
    float* x_ln   = (float*)(ws + 0 * MB);    // 16MB, dead after w-proj
    float* rbuf   = (float*)(ws + 16 * MB);   // 16MB, dead after scan
    float* kbuf   = (float*)(ws + 32 * MB);   // 16MB, dead after scan
    float* wbuf   = (float*)(ws + 48 * MB);   // 16MB, dead after scan
    float* state  = (float*)(ws + 64 * MB);   // 16MB, dead after concat
    float* hbuf   = (float*)(ws + 80 * MB);   // 16MB, live to end
    float* gates  = (float*)(ws + 96 * MB);   // 128KB
    float* hs     = (float*)(ws + 16 * MB);   // 32MB reuse r+k (after scan)
    float* prefix = (float*)(ws + 97 * MB);   // 64MB, live through TR experts
    float* kk     = (float*)(ws + 161 * MB);  // 64MB (FFN loop)
    float* rg     = (float*)(ws + 225 * MB);  // 16MB (FFN loop)
    float* qb     = (float*)(ws + 161 * MB);  // 16MB (TR loop, reuse kk)
    float* kpb    = (float*)(ws + 177 * MB);  // 64MB (TR loop)
    float* vpb    = (float*)(ws + 16 * MB);   // 64MB (TR loop, reuse r/k/w/state)
    float* attnb  = (float*)(ws + 0 * MB);    // 16MB (TR loop, reuse x_ln)
    (void)ws_size; (void)in_sizes; (void)n_in; (void)out_size;

    dim3 blk(256);
    auto grid = [](int M, int N) { return dim3(N / 128, M / 128); };

    // 1. ln1
    ln_kernel<<<BTn, blk, 0, stream>>>(x, ln1_w, ln1_b, x_ln);
    // 2-5. projections
    gemm_kernel<EP_NONE><<<grid(BTn, Cdim), blk, 0, stream>>>(x_ln, Wr, rbuf, BTn, Cdim, Cdim, nullptr, nullptr, 0);
    gemm_kernel<EP_NONE><<<grid(BTn, Cdim), blk, 0, stream>>>(x_ln, Wk, kbuf, BTn, Cdim, Cdim, nullptr, nullptr, 0);
    gemm_kernel<EP_NONE><<<grid(BTn, Cdim), blk, 0, stream>>>(x_ln, Wv, vflat, BTn, Cdim, Cdim, nullptr, nullptr, 0);
    gemm_kernel<EP_SIGB><<<grid(BTn, Cdim), blk, 0, stream>>>(x_ln, Ww, wbuf, BTn, Cdim, Cdim, w_bias, nullptr, 0);
    // 6. scan
    rwkv_scan_kernel<<<Bn * Hn, blk, 0, stream>>>(rbuf, kbuf, vflat, wbuf, state);
    // 7. x_after_att = x + state @ Wo  (into d_out)
    gemm_kernel<EP_ADD><<<grid(BTn, Cdim), blk, 0, stream>>>(state, Wo, xout, BTn, Cdim, Cdim, x, nullptr, 0);
    // 8. ln2
    ln_kernel<<<BTn, blk, 0, stream>>>(xout, ln2_w, ln2_b, hbuf);
    // 9. routing
    routing_kernel<<<BTn, blk, 0, stream>>>(hbuf, conf_w, conf_b, Wa, ba, cap, gates);
    // 10. concat [h, state]
    concat_kernel<<<(BTn * Cdim) / 256, blk, 0, stream>>>(hbuf, state, hs);
    // 11. prefix = tanh(hs @ Wb)  (BT, 2C) @ (2C, P*C)
    gemm_kernel<EP_TANH><<<grid(BTn, Pn * Cdim), blk, 0, stream>>>(hs, Wb, prefix, BTn, Pn * Cdim, 2 * Cdim, nullptr, nullptr, 0);
    // 12. FFN experts (dense, gate in epilogue)
    for (int e = 0; e < NRn; e++) {
        const float* We_r = ffn_Wr + (size_t)e * Cdim * Cdim;
        const float* We_k = ffn_Wk + (size_t)e * Cdim * FFn;
        const float* We_v = ffn_Wv + (size_t)e * FFn * Cdim;
        gemm_kernel<EP_SIG><<<grid(BTn, Cdim), blk, 0, stream>>>(hbuf, We_r, rg, BTn, Cdim, Cdim, nullptr, nullptr, 0);
        gemm_kernel<EP_RELU2><<<grid(BTn, FFn), blk, 0, stream>>>(hbuf, We_k, kk, BTn, FFn, Cdim, nullptr, nullptr, 0);
        gemm_kernel<EP_MOE><<<grid(BTn, Cdim), blk, 0, stream>>>(kk, We_v, xout, BTn, Cdim, FFn, gates + e, rg, En);
    }
    // 13. transformer experts
    for (int t = 0; t < NTn; t++) {
        int e = NRn + t;
        const float* Wq_t = tr_Wq + (size_t)t * Cdim * Cdim;
        const float* Wk_t = tr_Wk + (size_t)t * Cdim * Cdim;
        const float* Wv_t = tr_Wv + (size_t)t * Cdim * Cdim;
        const float* Wo_t = tr_Wo + (size_t)t * Cdim * Cdim;
        gemm_kernel<EP_NONE><<<grid(BTn, Cdim), blk, 0, stream>>>(hbuf, Wq_t, qb, BTn, Cdim, Cdim, nullptr, nullptr, 0);
        gemm_kernel<EP_NONE><<<grid(BTn * Pn, Cdim), blk, 0, stream>>>(prefix, Wk_t, kpb, BTn * Pn, Cdim, Cdim, nullptr, nullptr, 0);
        gemm_kernel<EP_NONE><<<grid(BTn * Pn, Cdim), blk, 0, stream>>>(prefix, Wv_t, vpb, BTn * Pn, Cdim, Cdim, nullptr, nullptr, 0);
        tr_attn_kernel<<<(BTn * Hn) / 4, blk, 0, stream>>>(qb, kpb, vpb, attnb);
        gemm_kernel<EP_MOE><<<grid(BTn, Cdim), blk, 0, stream>>>(attnb, Wo_t, xout, BTn, Cdim, Cdim, gates + e, nullptr, En);
    }
}

// Round 3
// 3488.142 us; speedup vs baseline: 3.6843x; 3.6843x over previous
//
#include <hip/hip_runtime.h>
#include <hip/hip_bf16.h>
#include <math.h>

// Problem constants
#define Bn   2
#define Tn   2048
#define Cdim 1024
#define HSn  64
#define En   8
#define NRn  6
#define Pn   4
#define Hn   16            // C/HS
#define FFn  4096          // 4*C
#define NTn  2
#define BTn  4096          // B*T

typedef __attribute__((ext_vector_type(8))) short bfrag;    // 8 bf16 (4 VGPRs)
typedef __attribute__((ext_vector_type(4))) float f32x4;

// async global->LDS, 16B per lane
__device__ __forceinline__ void gl_lds16(const void* g, void* l) {
    __builtin_amdgcn_global_load_lds(
        (const __attribute__((address_space(1))) unsigned int*)g,
        (__attribute__((address_space(3))) unsigned int*)l, 16, 0, 0);
}

// ---------------- LayerNorm (fp32 in, optional fp32 + bf16 out) ----------------
__global__ __launch_bounds__(256) void ln_kernel(const float* __restrict__ x,
                                                 const float* __restrict__ w,
                                                 const float* __restrict__ b,
                                                 float* __restrict__ out_f,
                                                 __hip_bfloat16* __restrict__ out_b) {
    int row = blockIdx.x;
    const float* xr = x + (size_t)row * Cdim;
    float s = 0.f, s2 = 0.f;
    for (int c = threadIdx.x; c < Cdim; c += 256) {
        float v = xr[c];
        s += v; s2 += v * v;
    }
    __shared__ float rs[256], rs2[256];
    rs[threadIdx.x] = s; rs2[threadIdx.x] = s2;
    __syncthreads();
    for (int st = 128; st > 0; st >>= 1) {
        if (threadIdx.x < st) {
            rs[threadIdx.x]  += rs[threadIdx.x + st];
            rs2[threadIdx.x] += rs2[threadIdx.x + st];
        }
        __syncthreads();
    }
    float mean = rs[0] / Cdim;
    float var  = rs2[0] / Cdim - mean * mean;
    float inv  = rsqrtf(var + 1e-5f);
    for (int c = threadIdx.x; c < Cdim; c += 256) {
        float v = (xr[c] - mean) * inv * w[c] + b[c];
        if (out_f) out_f[(size_t)row * Cdim + c] = v;
        if (out_b) out_b[(size_t)row * Cdim + c] = __float2bfloat16(v);
    }
}

// ---------------- fp32 vector GEMM (routing-critical path) ----------------
// C(M,N) = A(M,K) @ B(K,N), row-major. 128x128 tile, BK=8, 256 thr, 8x8/thr.
enum { FP_NONE = 0, FP_ADD = 1, FP_SIGB = 2 };

template <int EP>
__global__ __launch_bounds__(256) void gemm_kernel(
    const float* __restrict__ A, const float* __restrict__ B, float* __restrict__ C,
    int M, int N, int K,
    const float* __restrict__ aux1) {  // ADD: residual (M,N); SIGB: bias (N)
    __shared__ float As[8][128];
    __shared__ float Bs[8][128];
    int tid = threadIdx.x;
    int tx = tid & 15, ty = tid >> 4;
    int m0 = blockIdx.y * 128, n0 = blockIdx.x * 128;

    float acc[8][8];
#pragma unroll
    for (int i = 0; i < 8; i++)
#pragma unroll
        for (int j = 0; j < 8; j++) acc[i][j] = 0.f;

    int aRow = tid >> 1;
    int aCol = (tid & 1) * 4;
    int bRow = tid >> 5;
    int bCol = (tid & 31) * 4;
    const float* Aptr = A + (size_t)(m0 + aRow) * K + aCol;
    const float* Bptr = B + (size_t)bRow * N + n0 + bCol;

    for (int kt = 0; kt < K; kt += 8) {
        float4 a4 = *(const float4*)(Aptr + kt);
        float4 b4 = *(const float4*)(Bptr + (size_t)kt * N);
        As[aCol + 0][aRow] = a4.x;
        As[aCol + 1][aRow] = a4.y;
        As[aCol + 2][aRow] = a4.z;
        As[aCol + 3][aRow] = a4.w;
        *(float4*)&Bs[bRow][bCol] = b4;
        __syncthreads();
#pragma unroll
        for (int k = 0; k < 8; k++) {
            float4 a0 = *(const float4*)&As[k][ty * 8];
            float4 a1 = *(const float4*)&As[k][ty * 8 + 4];
            float4 b0 = *(const float4*)&Bs[k][tx * 8];
            float4 b1 = *(const float4*)&Bs[k][tx * 8 + 4];
            float av[8] = {a0.x, a0.y, a0.z, a0.w, a1.x, a1.y, a1.z, a1.w};
            float bv[8] = {b0.x, b0.y, b0.z, b0.w, b1.x, b1.y, b1.z, b1.w};
#pragma unroll
            for (int i = 0; i < 8; i++)
#pragma unroll
                for (int j = 0; j < 8; j++) acc[i][j] += av[i] * bv[j];
        }
        __syncthreads();
    }

#pragma unroll
    for (int i = 0; i < 8; i++) {
        int gm = m0 + ty * 8 + i;
#pragma unroll
        for (int j = 0; j < 8; j++) {
            int gn = n0 + tx * 8 + j;
            size_t idx = (size_t)gm * N + gn;
            float v = acc[i][j];
            if (EP == FP_NONE) {
                C[idx] = v;
            } else if (EP == FP_ADD) {
                C[idx] = aux1[idx] + v;
            } else if (EP == FP_SIGB) {
                C[idx] = 1.f / (1.f + expf(-(v + aux1[gn])));
            }
        }
    }
}

// ---------------- fp32 -> bf16 transposed weight conversion ----------------
// W: (K,N) row-major fp32  ->  Wt: (N,K) row-major bf16
__global__ __launch_bounds__(256) void convT_kernel(const float* __restrict__ W,
                                                    __hip_bfloat16* __restrict__ Wt,
                                                    int K, int N) {
    __shared__ float tile[32][33];
    int k0 = blockIdx.y * 32, n0 = blockIdx.x * 32;
    int tx = threadIdx.x, ty = threadIdx.y;  // (32,8)
#pragma unroll
    for (int i = 0; i < 32; i += 8)
        tile[ty + i][tx] = W[(size_t)(k0 + ty + i) * N + n0 + tx];
    __syncthreads();
#pragma unroll
    for (int i = 0; i < 32; i += 8)
        Wt[(size_t)(n0 + ty + i) * K + k0 + tx] = __float2bfloat16(tile[tx][ty + i]);
}

// ---------------- bf16 MFMA GEMM: C(M,N) = A(M,K) @ Bt(N,K)^T ----------------
// 128x128 tile, BK=64, 256 thr (4 waves, 2x2 of 64x64), 16x16x32 bf16 MFMA.
enum { EP_SIG = 0, EP_RELU2B = 1, EP_TANHB = 2, EP_BF16 = 3, EP_MOE = 4, EP_MOEM = 5 };

template <int EP>
__global__ __launch_bounds__(256) void bgemm_kernel(
    const __hip_bfloat16* __restrict__ A, const __hip_bfloat16* __restrict__ Bt,
    void* __restrict__ Cv, int M, int N, int K,
    const float* __restrict__ aux1,  // MOE*: gate base (stride gstride)
    const float* __restrict__ aux2,  // MOEM: fp32 multiplier (M,N)
    int gstride) {
    __shared__ __align__(16) __hip_bfloat16 Asm[128 * 64];
    __shared__ __align__(16) __hip_bfloat16 Bsm[128 * 64];
    int tid = threadIdx.x;
    int m0 = blockIdx.y * 128, n0 = blockIdx.x * 128;
    int l = tid & 63;
    int wv = tid >> 6;
    int wm = (wv >> 1) * 64, wn = (wv & 1) * 64;
    int lr = l & 15, lq = l >> 4;

    f32x4 acc[4][4];
#pragma unroll
    for (int i = 0; i < 4; i++)
#pragma unroll
        for (int j = 0; j < 4; j++) acc[i][j] = (f32x4){0.f, 0.f, 0.f, 0.f};

    const __hip_bfloat16* Abase = A  + (size_t)(m0 + (tid >> 3)) * K + ((tid & 7) << 3);
    const __hip_bfloat16* Bbase = Bt + (size_t)(n0 + (tid >> 3)) * K + ((tid & 7) << 3);

    for (int kt = 0; kt < K; kt += 64) {
#pragma unroll
        for (int c = 0; c < 4; c++) {
            gl_lds16(Abase + (size_t)(c * 32) * K + kt, Asm + c * 2048 + tid * 8);
            gl_lds16(Bbase + (size_t)(c * 32) * K + kt, Bsm + c * 2048 + tid * 8);
        }
        __syncthreads();
#pragma unroll
        for (int kc = 0; kc < 64; kc += 32) {
            bfrag af[4], bf[4];
#pragma unroll
            for (int mi = 0; mi < 4; mi++)
                af[mi] = *(const bfrag*)&Asm[(wm + mi * 16 + lr) * 64 + kc + lq * 8];
#pragma unroll
            for (int ni = 0; ni < 4; ni++)
                bf[ni] = *(const bfrag*)&Bsm[(wn + ni * 16 + lr) * 64 + kc + lq * 8];
#pragma unroll
            for (int mi = 0; mi < 4; mi++)
#pragma unroll
                for (int ni = 0; ni < 4; ni++)
                    acc[mi][ni] = __builtin_amdgcn_mfma_f32_16x16x32_bf16(
                        af[mi], bf[ni], acc[mi][ni], 0, 0, 0);
        }
        __syncthreads();
    }

    float* Cf = (float*)Cv;
    __hip_bfloat16* Cb = (__hip_bfloat16*)Cv;
#pragma unroll
    for (int mi = 0; mi < 4; mi++) {
#pragma unroll
        for (int r = 0; r < 4; r++) {
            int row = m0 + wm + mi * 16 + lq * 4 + r;
            float g = 0.f;
            if (EP == EP_MOE || EP == EP_MOEM) g = aux1[(size_t)row * gstride];
#pragma unroll
            for (int ni = 0; ni < 4; ni++) {
                int col = n0 + wn + ni * 16 + lr;
                size_t idx = (size_t)row * N + col;
                float v = acc[mi][ni][r];
                if (EP == EP_SIG) {
                    Cf[idx] = 1.f / (1.f + expf(-v));
                } else if (EP == EP_RELU2B) {
                    float t = fmaxf(v, 0.f);
                    Cb[idx] = __float2bfloat16(t * t);
                } else if (EP == EP_TANHB) {
                    Cb[idx] = __float2bfloat16(tanhf(v));
                } else if (EP == EP_BF16) {
                    Cb[idx] = __float2bfloat16(v);
                } else if (EP == EP_MOE) {
                    Cf[idx] += g * v;
                } else if (EP == EP_MOEM) {
                    Cf[idx] += g * aux2[idx] * v;
                }
            }
        }
    }
}

// ---------------- RWKV7 per-head scan (chunk-8 prefetch, 1 barrier/step) -------
__global__ __launch_bounds__(256) void rwkv_scan_kernel(
    const float* __restrict__ r, const float* __restrict__ k,
    const float* __restrict__ v, const float* __restrict__ w,
    float* __restrict__ y) {
    int bh = blockIdx.x;
    int b = bh >> 4, h = bh & 15;
    int tid = threadIdx.x;
    int j = tid & 63;
    int ig = tid >> 6;
    __shared__ float sbuf[2][4][64];  // [parity][r,k,v,w][j]
    __shared__ float red[2][4][64];   // [parity][ig][j]
    float S[16];
#pragma unroll
    for (int i = 0; i < 16; i++) S[i] = 0.f;

    size_t base = (size_t)b * Tn * Cdim + (size_t)h * HSn + j;
    const float* srcs[4] = {r, k, v, w};
    const float* myp = srcs[ig] + base;

    const int CH = 8;
    float buf[CH];
#pragma unroll
    for (int u = 0; u < CH; u++) buf[u] = myp[(size_t)u * Cdim];
    float part_prev = 0.f;

    for (int tc = 0; tc < Tn; tc += CH) {
        float nbuf[CH];
#pragma unroll
        for (int u = 0; u < CH; u++) {
            int t2 = tc + CH + u;
            nbuf[u] = (t2 < Tn) ? myp[(size_t)t2 * Cdim] : 0.f;
        }
#pragma unroll
        for (int u = 0; u < CH; u++) {
            int t = tc + u;
            int p = t & 1;
            sbuf[p][ig][j] = buf[u];
            red[p][ig][j] = part_prev;  // partials of step t-1
            __syncthreads();
            if (ig == 0 && t > 0) {
                y[base + (size_t)(t - 1) * Cdim] =
                    red[p][0][j] + red[p][1][j] + red[p][2][j] + red[p][3][j];
            }
            float vj = sbuf[p][2][j];
            const float* srp = sbuf[p][0];
            const float* skp = sbuf[p][1];
            const float* swp = sbuf[p][3];
            float part = 0.f;
#pragma unroll
            for (int ii = 0; ii < 16; ii++) {
                int i = (ig << 4) + ii;
                S[ii] = S[ii] * swp[i] + skp[i] * vj;
                part += srp[i] * S[ii];
            }
            part_prev = part;
        }
#pragma unroll
        for (int u = 0; u < CH; u++) buf[u] = nbuf[u];
    }
    int p = Tn & 1;
    red[p][ig][j] = part_prev;
    __syncthreads();
    if (ig == 0)
        y[base + (size_t)(Tn - 1) * Cdim] =
            red[p][0][j] + red[p][1][j] + red[p][2][j] + red[p][3][j];
}

// ---------------- Routing (fp32) ----------------
__global__ __launch_bounds__(256) void routing_kernel(
    const float* __restrict__ h, const float* __restrict__ conf_w,
    const float* __restrict__ conf_b, const float* __restrict__ Wa,
    const float* __restrict__ ba, const float* __restrict__ cap,
    float* __restrict__ gates) {
    int row = blockIdx.x;
    const float* hr = h + (size_t)row * Cdim;
    float pc[8], pa[8];
#pragma unroll
    for (int e = 0; e < 8; e++) { pc[e] = 0.f; pa[e] = 0.f; }
    for (int c = threadIdx.x; c < Cdim; c += 256) {
        float hv = hr[c];
#pragma unroll
        for (int e = 0; e < 8; e++) {
            pc[e] += hv * conf_w[(size_t)e * Cdim + c];
            pa[e] += hv * Wa[(size_t)c * En + e];
        }
    }
    __shared__ float red[256];
    __shared__ float vals[16];
    for (int e = 0; e < 16; e++) {
        red[threadIdx.x] = (e < 8) ? pc[e] : pa[e - 8];
        __syncthreads();
        for (int st = 128; st > 0; st >>= 1) {
            if (threadIdx.x < st) red[threadIdx.x] += red[threadIdx.x + st];
            __syncthreads();
        }
        if (threadIdx.x == 0) vals[e] = red[0];
        __syncthreads();
    }
    if (threadIdx.x == 0) {
        float conf[8], aff[8];
        for (int e = 0; e < 8; e++) {
            conf[e] = 1.f / (1.f + expf(-(vals[e] + conf_b[e])));
            aff[e]  = vals[8 + e] + ba[e];
        }
        float mx = aff[0];
        for (int e = 1; e < 8; e++) mx = fmaxf(mx, aff[e]);
        float se = 0.f, ex[8];
        for (int e = 0; e < 8; e++) { ex[e] = expf(aff[e] - mx); se += ex[e]; }
        float bids[8];
        for (int e = 0; e < 8; e++) bids[e] = conf[e] * cap[e] + ex[e] / se;
        int w0 = 0;
        for (int e = 1; e < 8; e++) if (bids[e] > bids[w0]) w0 = e;
        int w1 = -1;
        for (int e = 0; e < 8; e++) {
            if (e == w0) continue;
            if (w1 < 0 || bids[e] > bids[w1]) w1 = e;
        }
        float e1 = expf(bids[w1] - bids[w0]);
        float g0 = 1.f / (1.f + e1);
        float g1 = e1 / (1.f + e1);
        float* g = gates + (size_t)row * En;
        for (int e = 0; e < 8; e++) g[e] = 0.f;
        g[w0] = g0;
        g[w1] = g1;
    }
}

// ---------------- concat [h, state] (fp32 in) -> (BT, 2C) bf16 ----------------
__global__ __launch_bounds__(256) void concat_kernel(const float* __restrict__ h,
                                                     const float* __restrict__ st,
                                                     __hip_bfloat16* __restrict__ hs) {
    size_t i = (size_t)blockIdx.x * 256 + threadIdx.x;  // over BT*C
    size_t row = i / Cdim, c = i % Cdim;
    hs[row * (2 * Cdim) + c] = __float2bfloat16(h[i]);
    hs[row * (2 * Cdim) + Cdim + c] = __float2bfloat16(st[i]);
}

// ---------------- transformer-expert prefix attention (bf16 io) ----------------
__global__ __launch_bounds__(256) void tr_attn_kernel(
    const __hip_bfloat16* __restrict__ q, const __hip_bfloat16* __restrict__ kp,
    const __hip_bfloat16* __restrict__ vp, __hip_bfloat16* __restrict__ out) {
    int idx = blockIdx.x * 4 + (threadIdx.x >> 6);  // n*H + h
    int lane = threadIdx.x & 63;
    int n = idx / Hn, h = idx % Hn;
    float qd = __bfloat162float(q[(size_t)n * Cdim + (size_t)h * HSn + lane]);
    float s[4];
#pragma unroll
    for (int p = 0; p < 4; p++) {
        float t = qd * __bfloat162float(kp[((size_t)n * Pn + p) * Cdim + (size_t)h * HSn + lane]);
        for (int off = 32; off > 0; off >>= 1) t += __shfl_down(t, off);
        s[p] = __shfl(t, 0);
    }
    const float scale = 0.125f;
    float mx = fmaxf(fmaxf(s[0], s[1]), fmaxf(s[2], s[3])) * scale;
    float es = 0.f, a[4];
#pragma unroll
    for (int p = 0; p < 4; p++) { a[p] = expf(s[p] * scale - mx); es += a[p]; }
    float o = 0.f;
#pragma unroll
    for (int p = 0; p < 4; p++)
        o += (a[p] / es) * __bfloat162float(vp[((size_t)n * Pn + p) * Cdim + (size_t)h * HSn + lane]);
    out[(size_t)n * Cdim + (size_t)h * HSn + lane] = __float2bfloat16(o);
}

// ---------------- orchestration ----------------
extern "C" void kernel_launch(void* const* d_in, const int* in_sizes, int n_in,
                              void* d_out, int out_size, void* d_ws, size_t ws_size,
                              hipStream_t stream) {
    const float* x      = (const float*)d_in[0];
    const float* cap    = (const float*)d_in[2];
    const float* ln1_w  = (const float*)d_in[3];
    const float* ln1_b  = (const float*)d_in[4];
    const float* ln2_w  = (const float*)d_in[5];
    const float* ln2_b  = (const float*)d_in[6];
    const float* Wr     = (const float*)d_in[7];
    const float* Wk     = (const float*)d_in[8];
    const float* Wv     = (const float*)d_in[9];
    const float* Ww     = (const float*)d_in[10];
    const float* w_bias = (const float*)d_in[11];
    const float* Wo     = (const float*)d_in[12];
    const float* conf_w = (const float*)d_in[13];
    const float* conf_b = (const float*)d_in[14];
    const float* Wa     = (const float*)d_in[17];
    const float* ba     = (const float*)d_in[18];
    const float* Wb     = (const float*)d_in[19];
    const float* ffn_Wr = (const float*)d_in[20];
    const float* ffn_Wk = (const float*)d_in[21];
    const float* ffn_Wv = (const float*)d_in[22];
    const float* tr_Wq  = (const float*)d_in[23];
    const float* tr_Wk  = (const float*)d_in[24];
    const float* tr_Wv  = (const float*)d_in[25];
    const float* tr_Wo  = (const float*)d_in[26];

    float* xout  = (float*)d_out;                       // x_after_att, then += gated experts
    float* vflat = (float*)d_out + (size_t)BTn * Cdim;  // v_flat output (fp32)

    char* ws = (char*)d_ws;
    const size_t MB = 1ull << 20;
    float*          x_ln     = (float*)(ws + 0 * MB);             // 16MB, dead after projections
    float*          rbuf     = (float*)(ws + 16 * MB);            // 16MB, dead after scan
    float*          kbuf     = (float*)(ws + 32 * MB);            // 16MB, dead after scan
    float*          wbuf     = (float*)(ws + 48 * MB);            // 16MB, dead after scan
    float*          state    = (float*)(ws + 64 * MB);            // 16MB, dead after concat
    float*          hbuf     = (float*)(ws + 80 * MB);            // 16MB, dead after concat
    __hip_bfloat16* h_bf     = (__hip_bfloat16*)(ws + 96 * MB);   // 8MB, live to end
    float*          gates    = (float*)(ws + 104 * MB);           // 128KB
    __hip_bfloat16* prefix_bf= (__hip_bfloat16*)(ws + 105 * MB);  // 32MB, live through TR
    __hip_bfloat16* hs_bf    = (__hip_bfloat16*)(ws + 137 * MB);  // 16MB, dead after Wb gemm
    __hip_bfloat16* Wt_b     = (__hip_bfloat16*)(ws + 153 * MB);  // 16MB, dead after Wb gemm
    __hip_bfloat16* eWr_t    = (__hip_bfloat16*)(ws + 169 * MB);  // 2MB  (FFN loop)
    __hip_bfloat16* eWk_t    = (__hip_bfloat16*)(ws + 171 * MB);  // 8MB
    __hip_bfloat16* eWv_t    = (__hip_bfloat16*)(ws + 179 * MB);  // 8MB -> ends 187MB
    // FFN-phase overlays (x_ln, rbuf, kbuf dead):
    float*          rg       = (float*)(ws + 0 * MB);             // 16MB
    __hip_bfloat16* kk_bf    = (__hip_bfloat16*)(ws + 16 * MB);   // 32MB (16..48)
    // TR-phase overlays:
    __hip_bfloat16* qb_bf    = (__hip_bfloat16*)(ws + 48 * MB);   // 8MB (wbuf dead)
    __hip_bfloat16* kpb_bf   = (__hip_bfloat16*)(ws + 16 * MB);   // 32MB (kk dead)
    __hip_bfloat16* vpb_bf   = (__hip_bfloat16*)(ws + 64 * MB);   // 32MB (state+hbuf dead)
    __hip_bfloat16* attnb_bf = (__hip_bfloat16*)(ws + 137 * MB);  // 8MB (hs dead)
    __hip_bfloat16* tWq_t    = (__hip_bfloat16*)(ws + 169 * MB);  // 2MB each
    __hip_bfloat16* tWk_t    = (__hip_bfloat16*)(ws + 171 * MB);
    __hip_bfloat16* tWv_t    = (__hip_bfloat16*)(ws + 173 * MB);
    __hip_bfloat16* tWo_t    = (__hip_bfloat16*)(ws + 175 * MB);
    (void)ws_size; (void)in_sizes; (void)n_in; (void)out_size;

    dim3 blk(256);
    dim3 tblk(32, 8);
    auto grid = [](int M, int N) { return dim3(N / 128, M / 128); };
    auto tgrid = [](int K, int N) { return dim3(N / 32, K / 32); };

    // ===== attention stage: fp32 (feeds discontinuous routing; keep reference precision) =====
    // 1. ln1 -> fp32
    ln_kernel<<<BTn, blk, 0, stream>>>(x, ln1_w, ln1_b, x_ln, nullptr);
    // 2-5. projections (fp32 vector GEMM)
    gemm_kernel<FP_NONE><<<grid(BTn, Cdim), blk, 0, stream>>>(x_ln, Wr, rbuf, BTn, Cdim, Cdim, nullptr);
    gemm_kernel<FP_NONE><<<grid(BTn, Cdim), blk, 0, stream>>>(x_ln, Wk, kbuf, BTn, Cdim, Cdim, nullptr);
    gemm_kernel<FP_NONE><<<grid(BTn, Cdim), blk, 0, stream>>>(x_ln, Wv, vflat, BTn, Cdim, Cdim, nullptr);
    gemm_kernel<FP_SIGB><<<grid(BTn, Cdim), blk, 0, stream>>>(x_ln, Ww, wbuf, BTn, Cdim, Cdim, w_bias);
    // 6. scan (fp32 state)
    rwkv_scan_kernel<<<Bn * Hn, blk, 0, stream>>>(rbuf, kbuf, vflat, wbuf, state);
    // 7. x_after_att = x + state @ Wo (fp32, into d_out)
    gemm_kernel<FP_ADD><<<grid(BTn, Cdim), blk, 0, stream>>>(state, Wo, xout, BTn, Cdim, Cdim, x);
    // 8. ln2 -> fp32 (routing) + bf16 (experts)
    ln_kernel<<<BTn, blk, 0, stream>>>(xout, ln2_w, ln2_b, hbuf, h_bf);
    // 9. routing (fp32)
    routing_kernel<<<BTn, blk, 0, stream>>>(hbuf, conf_w, conf_b, Wa, ba, cap, gates);

    // ===== expert stage: bf16 MFMA (continuous math, gated accumulate) =====
    // 10. concat [h, state] -> bf16
    concat_kernel<<<(BTn * Cdim) / 256, blk, 0, stream>>>(hbuf, state, hs_bf);
    // 11. prefix = tanh(hs @ Wb) -> bf16
    convT_kernel<<<tgrid(2 * Cdim, Pn * Cdim), tblk, 0, stream>>>(Wb, Wt_b, 2 * Cdim, Pn * Cdim);
    bgemm_kernel<EP_TANHB><<<grid(BTn, Pn * Cdim), blk, 0, stream>>>(hs_bf, Wt_b, prefix_bf, BTn, Pn * Cdim, 2 * Cdim, nullptr, nullptr, 0);
    // 12. FFN experts
    for (int e = 0; e < NRn; e++) {
        convT_kernel<<<tgrid(Cdim, Cdim), tblk, 0, stream>>>(ffn_Wr + (size_t)e * Cdim * Cdim, eWr_t, Cdim, Cdim);
        convT_kernel<<<tgrid(Cdim, FFn), tblk, 0, stream>>>(ffn_Wk + (size_t)e * Cdim * FFn, eWk_t, Cdim, FFn);
        convT_kernel<<<tgrid(FFn, Cdim), tblk, 0, stream>>>(ffn_Wv + (size_t)e * FFn * Cdim, eWv_t, FFn, Cdim);
        bgemm_kernel<EP_SIG><<<grid(BTn, Cdim), blk, 0, stream>>>(h_bf, eWr_t, rg, BTn, Cdim, Cdim, nullptr, nullptr, 0);
        bgemm_kernel<EP_RELU2B><<<grid(BTn, FFn), blk, 0, stream>>>(h_bf, eWk_t, kk_bf, BTn, FFn, Cdim, nullptr, nullptr, 0);
        bgemm_kernel<EP_MOEM><<<grid(BTn, Cdim), blk, 0, stream>>>(kk_bf, eWv_t, xout, BTn, Cdim, FFn, gates + e, rg, En);
    }
    // 13. transformer experts
    for (int t = 0; t < NTn; t++) {
        int e = NRn + t;
        convT_kernel<<<tgrid(Cdim, Cdim), tblk, 0, stream>>>(tr_Wq + (size_t)t * Cdim * Cdim, tWq_t, Cdim, Cdim);
        convT_kernel<<<tgrid(Cdim, Cdim), tblk, 0, stream>>>(tr_Wk + (size_t)t * Cdim * Cdim, tWk_t, Cdim, Cdim);
        convT_kernel<<<tgrid(Cdim, Cdim), tblk, 0, stream>>>(tr_Wv + (size_t)t * Cdim * Cdim, tWv_t, Cdim, Cdim);
        convT_kernel<<<tgrid(Cdim, Cdim), tblk, 0, stream>>>(tr_Wo + (size_t)t * Cdim * Cdim, tWo_t, Cdim, Cdim);
        bgemm_kernel<EP_BF16><<<grid(BTn, Cdim), blk, 0, stream>>>(h_bf, tWq_t, qb_bf, BTn, Cdim, Cdim, nullptr, nullptr, 0);
        bgemm_kernel<EP_BF16><<<grid(BTn * Pn, Cdim), blk, 0, stream>>>(prefix_bf, tWk_t, kpb_bf, BTn * Pn, Cdim, Cdim, nullptr, nullptr, 0);
        bgemm_kernel<EP_BF16><<<grid(BTn * Pn, Cdim), blk, 0, stream>>>(prefix_bf, tWv_t, vpb_bf, BTn * Pn, Cdim, Cdim, nullptr, nullptr, 0);
        tr_attn_kernel<<<(BTn * Hn) / 4, blk, 0, stream>>>(qb_bf, kpb_bf, vpb_bf, attnb_bf);
        bgemm_kernel<EP_MOE><<<grid(BTn, Cdim), blk, 0, stream>>>(attnb_bf, tWo_t, xout, BTn, Cdim, Cdim, gates + e, nullptr, En);
    }
}

// Round 4
// 2171.169 us; speedup vs baseline: 5.9191x; 1.6066x over previous
//
#include <hip/hip_runtime.h>
#include <hip/hip_bf16.h>
#include <math.h>

// Problem constants
#define Bn   2
#define Tn   2048
#define Cdim 1024
#define HSn  64
#define En   8
#define NRn  6
#define Pn   4
#define Hn   16            // C/HS
#define FFn  4096          // 4*C
#define NTn  2
#define BTn  4096          // B*T
#define CHL  128           // scan chunk length
#define NCH  16            // Tn/CHL

typedef __attribute__((ext_vector_type(8))) short bfrag;    // 8 bf16 (4 VGPRs)
typedef __attribute__((ext_vector_type(4))) float f32x4;

__device__ __forceinline__ void gl_lds16(const void* g, void* l) {
    __builtin_amdgcn_global_load_lds(
        (const __attribute__((address_space(1))) unsigned int*)g,
        (__attribute__((address_space(3))) unsigned int*)l, 16, 0, 0);
}

__device__ __forceinline__ float sigm(float v) { return 1.f / (1.f + expf(-v)); }

// ---------------- LayerNorm: fp32 in -> optional {fp32, bf16-hi, bf16-lo} ------
__global__ __launch_bounds__(256) void ln_kernel(const float* __restrict__ x,
                                                 const float* __restrict__ w,
                                                 const float* __restrict__ b,
                                                 float* __restrict__ out_f,
                                                 __hip_bfloat16* __restrict__ out_hi,
                                                 __hip_bfloat16* __restrict__ out_lo) {
    int row = blockIdx.x;
    const float* xr = x + (size_t)row * Cdim;
    float s = 0.f, s2 = 0.f;
    for (int c = threadIdx.x; c < Cdim; c += 256) {
        float v = xr[c];
        s += v; s2 += v * v;
    }
    __shared__ float rs[256], rs2[256];
    rs[threadIdx.x] = s; rs2[threadIdx.x] = s2;
    __syncthreads();
    for (int st = 128; st > 0; st >>= 1) {
        if (threadIdx.x < st) {
            rs[threadIdx.x]  += rs[threadIdx.x + st];
            rs2[threadIdx.x] += rs2[threadIdx.x + st];
        }
        __syncthreads();
    }
    float mean = rs[0] / Cdim;
    float var  = rs2[0] / Cdim - mean * mean;
    float inv  = rsqrtf(var + 1e-5f);
    for (int c = threadIdx.x; c < Cdim; c += 256) {
        float v = (xr[c] - mean) * inv * w[c] + b[c];
        size_t idx = (size_t)row * Cdim + c;
        if (out_f) out_f[idx] = v;
        if (out_hi) {
            __hip_bfloat16 hi = __float2bfloat16(v);
            out_hi[idx] = hi;
            if (out_lo) out_lo[idx] = __float2bfloat16(v - __bfloat162float(hi));
        }
    }
}

// ---------------- fp32 -> bf16 transposed weight conversion (plain) ------------
__global__ __launch_bounds__(256) void convT_kernel(const float* __restrict__ W,
                                                    __hip_bfloat16* __restrict__ Wt,
                                                    int K, int N) {
    __shared__ float tile[32][33];
    int k0 = blockIdx.y * 32, n0 = blockIdx.x * 32;
    int tx = threadIdx.x, ty = threadIdx.y;  // (32,8)
#pragma unroll
    for (int i = 0; i < 32; i += 8)
        tile[ty + i][tx] = W[(size_t)(k0 + ty + i) * N + n0 + tx];
    __syncthreads();
#pragma unroll
    for (int i = 0; i < 32; i += 8)
        Wt[(size_t)(n0 + ty + i) * K + k0 + tx] = __float2bfloat16(tile[tx][ty + i]);
}

// ---------------- fp32 -> split bf16 hi/lo transposed conversion ---------------
__global__ __launch_bounds__(256) void convT_split_kernel(const float* __restrict__ W,
                                                          __hip_bfloat16* __restrict__ Wh,
                                                          __hip_bfloat16* __restrict__ Wl,
                                                          int K, int N) {
    __shared__ float tile[32][33];
    int k0 = blockIdx.y * 32, n0 = blockIdx.x * 32;
    int tx = threadIdx.x, ty = threadIdx.y;  // (32,8)
#pragma unroll
    for (int i = 0; i < 32; i += 8)
        tile[ty + i][tx] = W[(size_t)(k0 + ty + i) * N + n0 + tx];
    __syncthreads();
#pragma unroll
    for (int i = 0; i < 32; i += 8) {
        float v = tile[tx][ty + i];
        __hip_bfloat16 hi = __float2bfloat16(v);
        size_t o = (size_t)(n0 + ty + i) * K + k0 + tx;
        Wh[o] = hi;
        Wl[o] = __float2bfloat16(v - __bfloat162float(hi));
    }
}

// ---------- bf16x3 MFMA GEMM (fp32-grade): C = (Ah+Al)@(Bh+Bl)^T approx --------
// acc = AhBh + AhBl + AlBh. 128x128 tile, BK=64, 4 LDS arrays (64KB).
enum { EP3_QKVW = 0, EP3_ADD = 1 };

template <int EP>
__global__ __launch_bounds__(256) void bgemm3_kernel(
    const __hip_bfloat16* __restrict__ Ah, const __hip_bfloat16* __restrict__ Al,
    const __hip_bfloat16* __restrict__ Bh, const __hip_bfloat16* __restrict__ Bl,
    float* __restrict__ o0, float* __restrict__ o1,
    float* __restrict__ o2, float* __restrict__ o3,
    int M, int N, int K, const float* __restrict__ aux) {
    __shared__ __align__(16) __hip_bfloat16 Ahs[8192], Als[8192], Bhs[8192], Bls[8192];
    int tid = threadIdx.x;
    int m0 = blockIdx.y * 128, n0 = blockIdx.x * 128;
    int l = tid & 63, wv = tid >> 6;
    int wm = (wv >> 1) * 64, wn = (wv & 1) * 64;
    int lr = l & 15, lq = l >> 4;

    f32x4 acc[4][4];
#pragma unroll
    for (int i = 0; i < 4; i++)
#pragma unroll
        for (int j = 0; j < 4; j++) acc[i][j] = (f32x4){0.f, 0.f, 0.f, 0.f};

    size_t arow = (size_t)(m0 + (tid >> 3)) * K + ((tid & 7) << 3);
    size_t brow = (size_t)(n0 + (tid >> 3)) * K + ((tid & 7) << 3);

    for (int kt = 0; kt < K; kt += 64) {
#pragma unroll
        for (int c = 0; c < 4; c++) {
            size_t go = (size_t)(c * 32) * K + kt;
            gl_lds16(Ah + arow + go, Ahs + c * 2048 + tid * 8);
            gl_lds16(Al + arow + go, Als + c * 2048 + tid * 8);
            gl_lds16(Bh + brow + go, Bhs + c * 2048 + tid * 8);
            gl_lds16(Bl + brow + go, Bls + c * 2048 + tid * 8);
        }
        __syncthreads();
#pragma unroll
        for (int kc = 0; kc < 64; kc += 32) {
            bfrag ah[4], al[4], bh[4], bl[4];
#pragma unroll
            for (int mi = 0; mi < 4; mi++) {
                int off = (wm + mi * 16 + lr) * 64 + kc + lq * 8;
                ah[mi] = *(const bfrag*)&Ahs[off];
                al[mi] = *(const bfrag*)&Als[off];
            }
#pragma unroll
            for (int ni = 0; ni < 4; ni++) {
                int off = (wn + ni * 16 + lr) * 64 + kc + lq * 8;
                bh[ni] = *(const bfrag*)&Bhs[off];
                bl[ni] = *(const bfrag*)&Bls[off];
            }
#pragma unroll
            for (int mi = 0; mi < 4; mi++)
#pragma unroll
                for (int ni = 0; ni < 4; ni++) {
                    acc[mi][ni] = __builtin_amdgcn_mfma_f32_16x16x32_bf16(ah[mi], bh[ni], acc[mi][ni], 0, 0, 0);
                    acc[mi][ni] = __builtin_amdgcn_mfma_f32_16x16x32_bf16(al[mi], bh[ni], acc[mi][ni], 0, 0, 0);
                    acc[mi][ni] = __builtin_amdgcn_mfma_f32_16x16x32_bf16(ah[mi], bl[ni], acc[mi][ni], 0, 0, 0);
                }
        }
        __syncthreads();
    }

#pragma unroll
    for (int mi = 0; mi < 4; mi++) {
#pragma unroll
        for (int r = 0; r < 4; r++) {
            int row = m0 + wm + mi * 16 + lq * 4 + r;
#pragma unroll
            for (int ni = 0; ni < 4; ni++) {
                int col = n0 + wn + ni * 16 + lr;
                float v = acc[mi][ni][r];
                if (EP == EP3_QKVW) {
                    int sel = col >> 10, cc = col & 1023;
                    size_t idx = (size_t)row * 1024 + cc;
                    if (sel == 0) o0[idx] = v;
                    else if (sel == 1) o1[idx] = v;
                    else if (sel == 2) o2[idx] = v;
                    else o3[idx] = sigm(v + aux[cc]);
                } else {  // EP3_ADD
                    size_t idx = (size_t)row * N + col;
                    o0[idx] = aux[idx] + v;
                }
            }
        }
    }
}

// ---------------- plain bf16 MFMA GEMM (expert stage) --------------------------
enum { EP_TANHB = 0, EP_BF16 = 1, EP_MOE = 2, EP_MOEM = 3, EP_FFN1 = 4, EP_KV = 5 };

template <int EP>
__global__ __launch_bounds__(256) void bgemm_kernel(
    const __hip_bfloat16* __restrict__ A, const __hip_bfloat16* __restrict__ Bt,
    void* __restrict__ Cv, void* __restrict__ Cv2, int M, int N, int K,
    const float* __restrict__ aux1,  // MOE*: gate base (stride gstride)
    const float* __restrict__ aux2,  // MOEM: fp32 multiplier
    int gstride) {
    __shared__ __align__(16) __hip_bfloat16 Asm[8192];
    __shared__ __align__(16) __hip_bfloat16 Bsm[8192];
    int tid = threadIdx.x;
    int m0 = blockIdx.y * 128, n0 = blockIdx.x * 128;
    int l = tid & 63, wv = tid >> 6;
    int wm = (wv >> 1) * 64, wn = (wv & 1) * 64;
    int lr = l & 15, lq = l >> 4;

    f32x4 acc[4][4];
#pragma unroll
    for (int i = 0; i < 4; i++)
#pragma unroll
        for (int j = 0; j < 4; j++) acc[i][j] = (f32x4){0.f, 0.f, 0.f, 0.f};

    size_t arow = (size_t)(m0 + (tid >> 3)) * K + ((tid & 7) << 3);
    size_t brow = (size_t)(n0 + (tid >> 3)) * K + ((tid & 7) << 3);

    int ks = K / gridDim.z;
    int kbeg = blockIdx.z * ks, kend = kbeg + ks;

    for (int kt = kbeg; kt < kend; kt += 64) {
#pragma unroll
        for (int c = 0; c < 4; c++) {
            size_t go = (size_t)(c * 32) * K + kt;
            gl_lds16(A + arow + go, Asm + c * 2048 + tid * 8);
            gl_lds16(Bt + brow + go, Bsm + c * 2048 + tid * 8);
        }
        __syncthreads();
#pragma unroll
        for (int kc = 0; kc < 64; kc += 32) {
            bfrag af[4], bf[4];
#pragma unroll
            for (int mi = 0; mi < 4; mi++)
                af[mi] = *(const bfrag*)&Asm[(wm + mi * 16 + lr) * 64 + kc + lq * 8];
#pragma unroll
            for (int ni = 0; ni < 4; ni++)
                bf[ni] = *(const bfrag*)&Bsm[(wn + ni * 16 + lr) * 64 + kc + lq * 8];
#pragma unroll
            for (int mi = 0; mi < 4; mi++)
#pragma unroll
                for (int ni = 0; ni < 4; ni++)
                    acc[mi][ni] = __builtin_amdgcn_mfma_f32_16x16x32_bf16(
                        af[mi], bf[ni], acc[mi][ni], 0, 0, 0);
        }
        __syncthreads();
    }

    float* Cf = (float*)Cv;
    __hip_bfloat16* Cb = (__hip_bfloat16*)Cv;
#pragma unroll
    for (int mi = 0; mi < 4; mi++) {
#pragma unroll
        for (int r = 0; r < 4; r++) {
            int row = m0 + wm + mi * 16 + lq * 4 + r;
            float g = 0.f;
            if (EP == EP_MOE || EP == EP_MOEM) g = aux1[(size_t)row * gstride];
#pragma unroll
            for (int ni = 0; ni < 4; ni++) {
                int col = n0 + wn + ni * 16 + lr;
                float v = acc[mi][ni][r];
                if (EP == EP_TANHB) {
                    Cb[(size_t)row * N + col] = __float2bfloat16(tanhf(v));
                } else if (EP == EP_BF16) {
                    Cb[(size_t)row * N + col] = __float2bfloat16(v);
                } else if (EP == EP_MOE) {
                    Cf[(size_t)row * N + col] += g * v;
                } else if (EP == EP_MOEM) {
                    size_t idx = (size_t)row * N + col;
                    atomicAdd(&Cf[idx], g * aux2[idx] * v);
                } else if (EP == EP_FFN1) {
                    if ((col >> 10) == 0) {
                        Cf[(size_t)row * 1024 + col] = sigm(v);
                    } else {
                        float t = fmaxf(v, 0.f);
                        ((__hip_bfloat16*)Cv2)[(size_t)row * 4096 + col - 1024] =
                            __float2bfloat16(t * t);
                    }
                } else if (EP == EP_KV) {
                    if ((col >> 10) == 0)
                        Cb[(size_t)row * 1024 + col] = __float2bfloat16(v);
                    else
                        ((__hip_bfloat16*)Cv2)[(size_t)row * 1024 + col - 1024] =
                            __float2bfloat16(v);
                }
            }
        }
    }
}

// ---------------- chunked RWKV scan ----------------
// pass1: per chunk local M (state from zero) and P = prod(w). grid (NCH, 32).
__global__ __launch_bounds__(256) void scan_pass1(
    const float* __restrict__ k, const float* __restrict__ v,
    const float* __restrict__ w, float* __restrict__ Mbuf,
    float* __restrict__ Pbuf) {
    int c = blockIdx.x, bh = blockIdx.y;
    int b = bh >> 4, h = bh & 15;
    int tid = threadIdx.x, j = tid & 63, ig = tid >> 6;
    __shared__ float sbuf[2][3][64];  // [parity][k,v,w]
    float S[16], P[16];
#pragma unroll
    for (int ii = 0; ii < 16; ii++) { S[ii] = 0.f; P[ii] = 1.f; }

    size_t base = ((size_t)b * Tn + (size_t)c * CHL) * Cdim + (size_t)h * HSn + j;
    const float* srcs[3] = {k, v, w};
    const float* myp = (ig > 0) ? srcs[ig - 1] + base : k + base;

    const int CH = 8;
    float buf[CH];
#pragma unroll
    for (int u = 0; u < CH; u++) buf[u] = (ig > 0) ? myp[(size_t)u * Cdim] : 0.f;

    for (int tc = 0; tc < CHL; tc += CH) {
        float nbuf[CH];
#pragma unroll
        for (int u = 0; u < CH; u++) {
            int t2 = tc + CH + u;
            nbuf[u] = (ig > 0 && t2 < CHL) ? myp[(size_t)t2 * Cdim] : 0.f;
        }
#pragma unroll
        for (int u = 0; u < CH; u++) {
            int p = (tc + u) & 1;
            if (ig > 0) sbuf[p][ig - 1][j] = buf[u];
            __syncthreads();
            float vj = sbuf[p][1][j];
            const float* skp = sbuf[p][0];
            const float* swp = sbuf[p][2];
#pragma unroll
            for (int ii = 0; ii < 16; ii++) {
                int i = (ig << 4) + ii;
                float wi = swp[i];
                S[ii] = S[ii] * wi + skp[i] * vj;
                P[ii] *= wi;
            }
        }
#pragma unroll
        for (int u = 0; u < CH; u++) buf[u] = nbuf[u];
    }
    size_t mo = ((size_t)c * 32 + bh) * 4096;
#pragma unroll
    for (int ii = 0; ii < 16; ii++)
        Mbuf[mo + (size_t)((ig << 4) + ii) * 64 + j] = S[ii];
    if (j == 0) {
#pragma unroll
        for (int ii = 0; ii < 16; ii++)
            Pbuf[((size_t)c * 32 + bh) * 64 + (ig << 4) + ii] = P[ii];
    }
}

// pass2: sequential combine over chunks -> per-chunk initial state. grid (16,32).
__global__ __launch_bounds__(256) void scan_pass2(
    const float* __restrict__ Mbuf, const float* __restrict__ Pbuf,
    float* __restrict__ Sinb) {
    int bh = blockIdx.y;
    int idx = blockIdx.x * 256 + threadIdx.x;  // 0..4095
    int i = idx >> 6;
    float S = 0.f;
    for (int c = 0; c < NCH; c++) {
        size_t o = ((size_t)c * 32 + bh);
        Sinb[o * 4096 + idx] = S;
        S = Pbuf[o * 64 + i] * S + Mbuf[o * 4096 + idx];
    }
}

// pass3: replay chunk with correct initial state, emit y -> state hi/lo bf16.
__global__ __launch_bounds__(256) void scan_pass3(
    const float* __restrict__ r, const float* __restrict__ k,
    const float* __restrict__ v, const float* __restrict__ w,
    const float* __restrict__ Sinb,
    __hip_bfloat16* __restrict__ sh, __hip_bfloat16* __restrict__ sl) {
    int c = blockIdx.x, bh = blockIdx.y;
    int b = bh >> 4, h = bh & 15;
    int tid = threadIdx.x, j = tid & 63, ig = tid >> 6;
    __shared__ float sbuf[2][4][64];
    __shared__ float red[2][4][64];
    float S[16];
    size_t so = ((size_t)c * 32 + bh) * 4096;
#pragma unroll
    for (int ii = 0; ii < 16; ii++)
        S[ii] = Sinb[so + (size_t)((ig << 4) + ii) * 64 + j];

    size_t base = ((size_t)b * Tn + (size_t)c * CHL) * Cdim + (size_t)h * HSn + j;
    const float* srcs[4] = {r, k, v, w};
    const float* myp = srcs[ig] + base;

    const int CH = 8;
    float buf[CH];
#pragma unroll
    for (int u = 0; u < CH; u++) buf[u] = myp[(size_t)u * Cdim];
    float part_prev = 0.f;

    for (int tc = 0; tc < CHL; tc += CH) {
        float nbuf[CH];
#pragma unroll
        for (int u = 0; u < CH; u++) {
            int t2 = tc + CH + u;
            nbuf[u] = (t2 < CHL) ? myp[(size_t)t2 * Cdim] : 0.f;
        }
#pragma unroll
        for (int u = 0; u < CH; u++) {
            int t = tc + u;
            int p = t & 1;
            sbuf[p][ig][j] = buf[u];
            red[p][ig][j] = part_prev;
            __syncthreads();
            if (ig == 0 && t > 0) {
                float val = red[p][0][j] + red[p][1][j] + red[p][2][j] + red[p][3][j];
                __hip_bfloat16 hi = __float2bfloat16(val);
                size_t pos = base + (size_t)(t - 1) * Cdim;
                sh[pos] = hi;
                sl[pos] = __float2bfloat16(val - __bfloat162float(hi));
            }
            float vj = sbuf[p][2][j];
            const float* srp = sbuf[p][0];
            const float* skp = sbuf[p][1];
            const float* swp = sbuf[p][3];
            float part = 0.f;
#pragma unroll
            for (int ii = 0; ii < 16; ii++) {
                int i = (ig << 4) + ii;
                S[ii] = S[ii] * swp[i] + skp[i] * vj;
                part += srp[i] * S[ii];
            }
            part_prev = part;
        }
#pragma unroll
        for (int u = 0; u < CH; u++) buf[u] = nbuf[u];
    }
    red[0][ig][j] = part_prev;
    __syncthreads();
    if (ig == 0) {
        float val = red[0][0][j] + red[0][1][j] + red[0][2][j] + red[0][3][j];
        __hip_bfloat16 hi = __float2bfloat16(val);
        size_t pos = base + (size_t)(CHL - 1) * Cdim;
        sh[pos] = hi;
        sl[pos] = __float2bfloat16(val - __bfloat162float(hi));
    }
}

// ---------------- Routing (fp32) ----------------
__global__ __launch_bounds__(256) void routing_kernel(
    const float* __restrict__ h, const float* __restrict__ conf_w,
    const float* __restrict__ conf_b, const float* __restrict__ Wa,
    const float* __restrict__ ba, const float* __restrict__ cap,
    float* __restrict__ gates) {
    int row = blockIdx.x;
    const float* hr = h + (size_t)row * Cdim;
    float pc[8], pa[8];
#pragma unroll
    for (int e = 0; e < 8; e++) { pc[e] = 0.f; pa[e] = 0.f; }
    for (int c = threadIdx.x; c < Cdim; c += 256) {
        float hv = hr[c];
#pragma unroll
        for (int e = 0; e < 8; e++) {
            pc[e] += hv * conf_w[(size_t)e * Cdim + c];
            pa[e] += hv * Wa[(size_t)c * En + e];
        }
    }
    __shared__ float red[256];
    __shared__ float vals[16];
    for (int e = 0; e < 16; e++) {
        red[threadIdx.x] = (e < 8) ? pc[e] : pa[e - 8];
        __syncthreads();
        for (int st = 128; st > 0; st >>= 1) {
            if (threadIdx.x < st) red[threadIdx.x] += red[threadIdx.x + st];
            __syncthreads();
        }
        if (threadIdx.x == 0) vals[e] = red[0];
        __syncthreads();
    }
    if (threadIdx.x == 0) {
        float conf[8], aff[8];
        for (int e = 0; e < 8; e++) {
            conf[e] = sigm(vals[e] + conf_b[e]);
            aff[e]  = vals[8 + e] + ba[e];
        }
        float mx = aff[0];
        for (int e = 1; e < 8; e++) mx = fmaxf(mx, aff[e]);
        float se = 0.f, ex[8];
        for (int e = 0; e < 8; e++) { ex[e] = expf(aff[e] - mx); se += ex[e]; }
        float bids[8];
        for (int e = 0; e < 8; e++) bids[e] = conf[e] * cap[e] + ex[e] / se;
        int w0 = 0;
        for (int e = 1; e < 8; e++) if (bids[e] > bids[w0]) w0 = e;
        int w1 = -1;
        for (int e = 0; e < 8; e++) {
            if (e == w0) continue;
            if (w1 < 0 || bids[e] > bids[w1]) w1 = e;
        }
        float e1 = expf(bids[w1] - bids[w0]);
        float g0 = 1.f / (1.f + e1);
        float g1 = e1 / (1.f + e1);
        float* g = gates + (size_t)row * En;
        for (int e = 0; e < 8; e++) g[e] = 0.f;
        g[w0] = g0;
        g[w1] = g1;
    }
}

// ---------------- concat [h(fp32), state(bf16)] -> (BT, 2C) bf16 ----------------
__global__ __launch_bounds__(256) void concat_kernel(const float* __restrict__ h,
                                                     const __hip_bfloat16* __restrict__ st,
                                                     __hip_bfloat16* __restrict__ hs) {
    size_t i = (size_t)blockIdx.x * 256 + threadIdx.x;
    size_t row = i / Cdim, c = i % Cdim;
    hs[row * (2 * Cdim) + c] = __float2bfloat16(h[i]);
    hs[row * (2 * Cdim) + Cdim + c] = st[i];
}

// ---------------- transformer-expert prefix attention (bf16 io) ----------------
__global__ __launch_bounds__(256) void tr_attn_kernel(
    const __hip_bfloat16* __restrict__ q, const __hip_bfloat16* __restrict__ kp,
    const __hip_bfloat16* __restrict__ vp, __hip_bfloat16* __restrict__ out) {
    int idx = blockIdx.x * 4 + (threadIdx.x >> 6);  // n*H + h
    int lane = threadIdx.x & 63;
    int n = idx / Hn, h = idx % Hn;
    float qd = __bfloat162float(q[(size_t)n * Cdim + (size_t)h * HSn + lane]);
    float s[4];
#pragma unroll
    for (int p = 0; p < 4; p++) {
        float t = qd * __bfloat162float(kp[((size_t)n * Pn + p) * Cdim + (size_t)h * HSn + lane]);
        for (int off = 32; off > 0; off >>= 1) t += __shfl_down(t, off);
        s[p] = __shfl(t, 0);
    }
    const float scale = 0.125f;
    float mx = fmaxf(fmaxf(s[0], s[1]), fmaxf(s[2], s[3])) * scale;
    float es = 0.f, a[4];
#pragma unroll
    for (int p = 0; p < 4; p++) { a[p] = expf(s[p] * scale - mx); es += a[p]; }
    float o = 0.f;
#pragma unroll
    for (int p = 0; p < 4; p++)
        o += (a[p] / es) * __bfloat162float(vp[((size_t)n * Pn + p) * Cdim + (size_t)h * HSn + lane]);
    out[(size_t)n * Cdim + (size_t)h * HSn + lane] = __float2bfloat16(o);
}

// ---------------- orchestration ----------------
extern "C" void kernel_launch(void* const* d_in, const int* in_sizes, int n_in,
                              void* d_out, int out_size, void* d_ws, size_t ws_size,
                              hipStream_t stream) {
    const float* x      = (const float*)d_in[0];
    const float* cap    = (const float*)d_in[2];
    const float* ln1_w  = (const float*)d_in[3];
    const float* ln1_b  = (const float*)d_in[4];
    const float* ln2_w  = (const float*)d_in[5];
    const float* ln2_b  = (const float*)d_in[6];
    const float* Wr     = (const float*)d_in[7];
    const float* Wk     = (const float*)d_in[8];
    const float* Wv     = (const float*)d_in[9];
    const float* Ww     = (const float*)d_in[10];
    const float* w_bias = (const float*)d_in[11];
    const float* Wo     = (const float*)d_in[12];
    const float* conf_w = (const float*)d_in[13];
    const float* conf_b = (const float*)d_in[14];
    const float* Wa     = (const float*)d_in[17];
    const float* ba     = (const float*)d_in[18];
    const float* Wb     = (const float*)d_in[19];
    const float* ffn_Wr = (const float*)d_in[20];
    const float* ffn_Wk = (const float*)d_in[21];
    const float* ffn_Wv = (const float*)d_in[22];
    const float* tr_Wq  = (const float*)d_in[23];
    const float* tr_Wk  = (const float*)d_in[24];
    const float* tr_Wv  = (const float*)d_in[25];
    const float* tr_Wo  = (const float*)d_in[26];

    float* xout  = (float*)d_out;
    float* vflat = (float*)d_out + (size_t)BTn * Cdim;

    char* ws = (char*)d_ws;
    const size_t MB = 1ull << 20;
    // attention phase
    __hip_bfloat16* xln_hi  = (__hip_bfloat16*)(ws + 0 * MB);    // 8MB
    __hip_bfloat16* xln_lo  = (__hip_bfloat16*)(ws + 8 * MB);    // 8MB
    __hip_bfloat16* Wall_hi = (__hip_bfloat16*)(ws + 16 * MB);   // 8MB
    __hip_bfloat16* Wall_lo = (__hip_bfloat16*)(ws + 24 * MB);   // 8MB
    float*          rbuf    = (float*)(ws + 32 * MB);            // 16MB
    float*          kbuf    = (float*)(ws + 48 * MB);            // 16MB
    float*          wbuf    = (float*)(ws + 64 * MB);            // 16MB
    float*          Pbuf    = (float*)(ws + 80 * MB);            // 128KB
    __hip_bfloat16* Wo_hi   = (__hip_bfloat16*)(ws + 81 * MB);   // 2MB
    __hip_bfloat16* Wo_lo   = (__hip_bfloat16*)(ws + 83 * MB);   // 2MB
    float*          Mbuf    = (float*)(ws + 0 * MB);             // 8MB (xln dead)
    float*          Sinb    = (float*)(ws + 8 * MB);             // 8MB
    __hip_bfloat16* st_hi   = (__hip_bfloat16*)(ws + 16 * MB);   // 8MB (Wall dead)
    __hip_bfloat16* st_lo   = (__hip_bfloat16*)(ws + 24 * MB);   // 8MB
    float*          hbuf    = (float*)(ws + 32 * MB);            // 16MB (rbuf dead)
    __hip_bfloat16* h_bf    = (__hip_bfloat16*)(ws + 48 * MB);   // 8MB (kbuf dead)
    float*          gates   = (float*)(ws + 56 * MB);            // 128KB
    __hip_bfloat16* hs_bf   = (__hip_bfloat16*)(ws + 57 * MB);   // 16MB
    __hip_bfloat16* Wt_b    = (__hip_bfloat16*)(ws + 121 * MB);  // 16MB
    __hip_bfloat16* prefix  = (__hip_bfloat16*)(ws + 89 * MB);   // 32MB
    // FFN phase
    __hip_bfloat16* eWall   = (__hip_bfloat16*)(ws + 0 * MB);    // 10MB (scan bufs dead)
    __hip_bfloat16* eWv_t   = (__hip_bfloat16*)(ws + 10 * MB);   // 8MB
    float*          rg      = (float*)(ws + 32 * MB);            // 16MB (hbuf dead)
    __hip_bfloat16* kk_bf   = (__hip_bfloat16*)(ws + 57 * MB);   // 32MB (hs dead)
    // TR phase
    __hip_bfloat16* tkv     = (__hip_bfloat16*)(ws + 0 * MB);    // 4MB
    __hip_bfloat16* tq      = (__hip_bfloat16*)(ws + 4 * MB);    // 2MB
    __hip_bfloat16* to_     = (__hip_bfloat16*)(ws + 6 * MB);    // 2MB
    __hip_bfloat16* qb_bf   = (__hip_bfloat16*)(ws + 10 * MB);   // 8MB
    __hip_bfloat16* attnb   = (__hip_bfloat16*)(ws + 18 * MB);   // 8MB
    __hip_bfloat16* kpb_bf  = (__hip_bfloat16*)(ws + 57 * MB);   // 32MB (kk dead)
    __hip_bfloat16* vpb_bf  = (__hip_bfloat16*)(ws + 121 * MB);  // 32MB (Wt_b dead)
    (void)ws_size; (void)in_sizes; (void)n_in; (void)out_size;

    dim3 blk(256);
    dim3 tblk(32, 8);
    auto grid  = [](int M, int N) { return dim3(N / 128, M / 128); };
    auto tgrid = [](int K, int N) { return dim3(N / 32, K / 32); };
    const size_t CC = (size_t)Cdim * Cdim;

    // 0. attention weight conversions (split hi/lo, transposed)
    convT_split_kernel<<<tgrid(Cdim, Cdim), tblk, 0, stream>>>(Wr, Wall_hi, Wall_lo, Cdim, Cdim);
    convT_split_kernel<<<tgrid(Cdim, Cdim), tblk, 0, stream>>>(Wk, Wall_hi + CC, Wall_lo + CC, Cdim, Cdim);
    convT_split_kernel<<<tgrid(Cdim, Cdim), tblk, 0, stream>>>(Wv, Wall_hi + 2 * CC, Wall_lo + 2 * CC, Cdim, Cdim);
    convT_split_kernel<<<tgrid(Cdim, Cdim), tblk, 0, stream>>>(Ww, Wall_hi + 3 * CC, Wall_lo + 3 * CC, Cdim, Cdim);
    convT_split_kernel<<<tgrid(Cdim, Cdim), tblk, 0, stream>>>(Wo, Wo_hi, Wo_lo, Cdim, Cdim);
    convT_kernel<<<tgrid(2 * Cdim, Pn * Cdim), tblk, 0, stream>>>(Wb, Wt_b, 2 * Cdim, Pn * Cdim);

    // 1. ln1 -> hi/lo
    ln_kernel<<<BTn, blk, 0, stream>>>(x, ln1_w, ln1_b, nullptr, xln_hi, xln_lo);
    // 2. fused r/k/v/w projections (bf16x3, fp32-grade)
    bgemm3_kernel<EP3_QKVW><<<grid(BTn, 4 * Cdim), blk, 0, stream>>>(
        xln_hi, xln_lo, Wall_hi, Wall_lo, rbuf, kbuf, vflat, wbuf, BTn, 4 * Cdim, Cdim, w_bias);
    // 3. chunked scan
    scan_pass1<<<dim3(NCH, 32), blk, 0, stream>>>(kbuf, vflat, wbuf, Mbuf, Pbuf);
    scan_pass2<<<dim3(16, 32), blk, 0, stream>>>(Mbuf, Pbuf, Sinb);
    scan_pass3<<<dim3(NCH, 32), blk, 0, stream>>>(rbuf, kbuf, vflat, wbuf, Sinb, st_hi, st_lo);
    // 4. x_after_att = x + state @ Wo
    bgemm3_kernel<EP3_ADD><<<grid(BTn, Cdim), blk, 0, stream>>>(
        st_hi, st_lo, Wo_hi, Wo_lo, xout, nullptr, nullptr, nullptr, BTn, Cdim, Cdim, x);
    // 5. ln2 -> fp32 (routing) + bf16 (experts)
    ln_kernel<<<BTn, blk, 0, stream>>>(xout, ln2_w, ln2_b, hbuf, h_bf, nullptr);
    // 6. routing
    routing_kernel<<<BTn, blk, 0, stream>>>(hbuf, conf_w, conf_b, Wa, ba, cap, gates);
    // 7. concat + bridge prefix
    concat_kernel<<<(BTn * Cdim) / 256, blk, 0, stream>>>(hbuf, st_hi, hs_bf);
    bgemm_kernel<EP_TANHB><<<grid(BTn, Pn * Cdim), blk, 0, stream>>>(
        hs_bf, Wt_b, prefix, nullptr, BTn, Pn * Cdim, 2 * Cdim, nullptr, nullptr, 0);
    // 8. FFN experts
    for (int e = 0; e < NRn; e++) {
        convT_kernel<<<tgrid(Cdim, Cdim), tblk, 0, stream>>>(ffn_Wr + (size_t)e * CC, eWall, Cdim, Cdim);
        convT_kernel<<<tgrid(Cdim, FFn), tblk, 0, stream>>>(ffn_Wk + (size_t)e * Cdim * FFn, eWall + (size_t)Cdim * Cdim, Cdim, FFn);
        convT_kernel<<<tgrid(FFn, Cdim), tblk, 0, stream>>>(ffn_Wv + (size_t)e * FFn * Cdim, eWv_t, FFn, Cdim);
        bgemm_kernel<EP_FFN1><<<grid(BTn, 5 * Cdim), blk, 0, stream>>>(
            h_bf, eWall, rg, kk_bf, BTn, 5 * Cdim, Cdim, nullptr, nullptr, 0);
        bgemm_kernel<EP_MOEM><<<dim3(Cdim / 128, BTn / 128, 2), blk, 0, stream>>>(
            kk_bf, eWv_t, xout, nullptr, BTn, Cdim, FFn, gates + e, rg, En);
    }
    // 9. transformer experts
    for (int t = 0; t < NTn; t++) {
        int e = NRn + t;
        convT_kernel<<<tgrid(Cdim, Cdim), tblk, 0, stream>>>(tr_Wk + (size_t)t * CC, tkv, Cdim, Cdim);
        convT_kernel<<<tgrid(Cdim, Cdim), tblk, 0, stream>>>(tr_Wv + (size_t)t * CC, tkv + CC, Cdim, Cdim);
        convT_kernel<<<tgrid(Cdim, Cdim), tblk, 0, stream>>>(tr_Wq + (size_t)t * CC, tq, Cdim, Cdim);
        convT_kernel<<<tgrid(Cdim, Cdim), tblk, 0, stream>>>(tr_Wo + (size_t)t * CC, to_, Cdim, Cdim);
        bgemm_kernel<EP_KV><<<grid(BTn * Pn, 2 * Cdim), blk, 0, stream>>>(
            prefix, tkv, kpb_bf, vpb_bf, BTn * Pn, 2 * Cdim, Cdim, nullptr, nullptr, 0);
        bgemm_kernel<EP_BF16><<<grid(BTn, Cdim), blk, 0, stream>>>(
            h_bf, tq, qb_bf, nullptr, BTn, Cdim, Cdim, nullptr, nullptr, 0);
        tr_attn_kernel<<<(BTn * Hn) / 4, blk, 0, stream>>>(qb_bf, kpb_bf, vpb_bf, attnb);
        bgemm_kernel<EP_MOE><<<grid(BTn, Cdim), blk, 0, stream>>>(
            attnb, to_, xout, nullptr, BTn, Cdim, Cdim, gates + e, nullptr, En);
    }
}

// Round 5
// 1970.913 us; speedup vs baseline: 6.5205x; 1.1016x over previous
//
#include <hip/hip_runtime.h>
#include <hip/hip_bf16.h>
#include <math.h>

// Problem constants
#define Bn   2
#define Tn   2048
#define Cdim 1024
#define HSn  64
#define En   8
#define NRn  6
#define Pn   4
#define Hn   16            // C/HS
#define FFn  4096          // 4*C
#define NTn  2
#define BTn  4096          // B*T
#define CHL  128           // scan chunk length
#define NCH  16            // Tn/CHL

typedef __attribute__((ext_vector_type(8))) short bfrag;    // 8 bf16 (4 VGPRs)
typedef __attribute__((ext_vector_type(4))) float f32x4;

__device__ __forceinline__ void gl_lds16(const void* g, void* l) {
    __builtin_amdgcn_global_load_lds(
        (const __attribute__((address_space(1))) unsigned int*)g,
        (__attribute__((address_space(3))) unsigned int*)l, 16, 0, 0);
}

__device__ __forceinline__ float sigm(float v) { return 1.f / (1.f + expf(-v)); }

// ---------------- LayerNorm: fp32 in -> optional {fp32, bf16-hi, bf16-lo} ------
__global__ __launch_bounds__(256) void ln_kernel(const float* __restrict__ x,
                                                 const float* __restrict__ w,
                                                 const float* __restrict__ b,
                                                 float* __restrict__ out_f,
                                                 __hip_bfloat16* __restrict__ out_hi,
                                                 __hip_bfloat16* __restrict__ out_lo) {
    int row = blockIdx.x;
    const float* xr = x + (size_t)row * Cdim;
    float s = 0.f, s2 = 0.f;
    for (int c = threadIdx.x; c < Cdim; c += 256) {
        float v = xr[c];
        s += v; s2 += v * v;
    }
    __shared__ float rs[256], rs2[256];
    rs[threadIdx.x] = s; rs2[threadIdx.x] = s2;
    __syncthreads();
    for (int st = 128; st > 0; st >>= 1) {
        if (threadIdx.x < st) {
            rs[threadIdx.x]  += rs[threadIdx.x + st];
            rs2[threadIdx.x] += rs2[threadIdx.x + st];
        }
        __syncthreads();
    }
    float mean = rs[0] / Cdim;
    float var  = rs2[0] / Cdim - mean * mean;
    float inv  = rsqrtf(var + 1e-5f);
    for (int c = threadIdx.x; c < Cdim; c += 256) {
        float v = (xr[c] - mean) * inv * w[c] + b[c];
        size_t idx = (size_t)row * Cdim + c;
        if (out_f) out_f[idx] = v;
        if (out_hi) {
            __hip_bfloat16 hi = __float2bfloat16(v);
            out_hi[idx] = hi;
            if (out_lo) out_lo[idx] = __float2bfloat16(v - __bfloat162float(hi));
        }
    }
}

// ---------------- fp32 -> bf16 transposed weight conversion (plain) ------------
__global__ __launch_bounds__(256) void convT_kernel(const float* __restrict__ W,
                                                    __hip_bfloat16* __restrict__ Wt,
                                                    int K, int N) {
    __shared__ float tile[32][33];
    int k0 = blockIdx.y * 32, n0 = blockIdx.x * 32;
    int tx = threadIdx.x, ty = threadIdx.y;  // (32,8)
#pragma unroll
    for (int i = 0; i < 32; i += 8)
        tile[ty + i][tx] = W[(size_t)(k0 + ty + i) * N + n0 + tx];
    __syncthreads();
#pragma unroll
    for (int i = 0; i < 32; i += 8)
        Wt[(size_t)(n0 + ty + i) * K + k0 + tx] = __float2bfloat16(tile[tx][ty + i]);
}

// ---------------- fp32 -> split bf16 hi/lo transposed conversion ---------------
__global__ __launch_bounds__(256) void convT_split_kernel(const float* __restrict__ W,
                                                          __hip_bfloat16* __restrict__ Wh,
                                                          __hip_bfloat16* __restrict__ Wl,
                                                          int K, int N) {
    __shared__ float tile[32][33];
    int k0 = blockIdx.y * 32, n0 = blockIdx.x * 32;
    int tx = threadIdx.x, ty = threadIdx.y;  // (32,8)
#pragma unroll
    for (int i = 0; i < 32; i += 8)
        tile[ty + i][tx] = W[(size_t)(k0 + ty + i) * N + n0 + tx];
    __syncthreads();
#pragma unroll
    for (int i = 0; i < 32; i += 8) {
        float v = tile[tx][ty + i];
        __hip_bfloat16 hi = __float2bfloat16(v);
        size_t o = (size_t)(n0 + ty + i) * K + k0 + tx;
        Wh[o] = hi;
        Wl[o] = __float2bfloat16(v - __bfloat162float(hi));
    }
}

// LDS swizzle: element (row r, chunk q of 8 bf16) lives at r*64 + ((q^(r&7))<<3).
// Staging lane i therefore loads global chunk ((i&7)^((i>>3)&7)) of row (i>>3).

// ---------- bf16x3 MFMA GEMM (fp32-grade): C = (Ah+Al)@(Bh+Bl)^T approx --------
enum { EP3_QKVW = 0, EP3_ADD = 1 };

template <int EP>
__global__ __launch_bounds__(256) void bgemm3_kernel(
    const __hip_bfloat16* __restrict__ Ah, const __hip_bfloat16* __restrict__ Al,
    const __hip_bfloat16* __restrict__ Bh, const __hip_bfloat16* __restrict__ Bl,
    float* __restrict__ o0, float* __restrict__ o1,
    float* __restrict__ o2, float* __restrict__ o3,
    int M, int N, int K, const float* __restrict__ aux) {
    __shared__ __align__(16) __hip_bfloat16 Ahs[8192], Als[8192], Bhs[8192], Bls[8192];
    int tid = threadIdx.x;
    int m0 = blockIdx.y * 128, n0 = blockIdx.x * 128;
    int l = tid & 63, wv = tid >> 6;
    int wm = (wv >> 1) * 64, wn = (wv & 1) * 64;
    int lr = l & 15, lq = l >> 4;

    f32x4 acc[4][4];
#pragma unroll
    for (int i = 0; i < 4; i++)
#pragma unroll
        for (int j = 0; j < 4; j++) acc[i][j] = (f32x4){0.f, 0.f, 0.f, 0.f};

    int srow = tid >> 3;
    int sq = (tid & 7) ^ (srow & 7);           // swizzled chunk
    size_t arow = (size_t)(m0 + srow) * K + (sq << 3);
    size_t brow = (size_t)(n0 + srow) * K + (sq << 3);

    for (int kt = 0; kt < K; kt += 64) {
#pragma unroll
        for (int c = 0; c < 4; c++) {
            size_t go = (size_t)(c * 32) * K + kt;
            gl_lds16(Ah + arow + go, Ahs + c * 2048 + tid * 8);
            gl_lds16(Al + arow + go, Als + c * 2048 + tid * 8);
            gl_lds16(Bh + brow + go, Bhs + c * 2048 + tid * 8);
            gl_lds16(Bl + brow + go, Bls + c * 2048 + tid * 8);
        }
        __syncthreads();
#pragma unroll
        for (int kc = 0; kc < 64; kc += 32) {
            bfrag ah[4], al[4], bh[4], bl[4];
#pragma unroll
            for (int mi = 0; mi < 4; mi++) {
                int rr = wm + mi * 16 + lr;
                int off = rr * 64 + ((((kc >> 3) + lq) ^ (rr & 7)) << 3);
                ah[mi] = *(const bfrag*)&Ahs[off];
                al[mi] = *(const bfrag*)&Als[off];
            }
#pragma unroll
            for (int ni = 0; ni < 4; ni++) {
                int rr = wn + ni * 16 + lr;
                int off = rr * 64 + ((((kc >> 3) + lq) ^ (rr & 7)) << 3);
                bh[ni] = *(const bfrag*)&Bhs[off];
                bl[ni] = *(const bfrag*)&Bls[off];
            }
#pragma unroll
            for (int mi = 0; mi < 4; mi++)
#pragma unroll
                for (int ni = 0; ni < 4; ni++) {
                    acc[mi][ni] = __builtin_amdgcn_mfma_f32_16x16x32_bf16(ah[mi], bh[ni], acc[mi][ni], 0, 0, 0);
                    acc[mi][ni] = __builtin_amdgcn_mfma_f32_16x16x32_bf16(al[mi], bh[ni], acc[mi][ni], 0, 0, 0);
                    acc[mi][ni] = __builtin_amdgcn_mfma_f32_16x16x32_bf16(ah[mi], bl[ni], acc[mi][ni], 0, 0, 0);
                }
        }
        __syncthreads();
    }

#pragma unroll
    for (int mi = 0; mi < 4; mi++) {
#pragma unroll
        for (int r = 0; r < 4; r++) {
            int row = m0 + wm + mi * 16 + lq * 4 + r;
#pragma unroll
            for (int ni = 0; ni < 4; ni++) {
                int col = n0 + wn + ni * 16 + lr;
                float v = acc[mi][ni][r];
                if (EP == EP3_QKVW) {
                    int sel = col >> 10, cc = col & 1023;
                    size_t idx = (size_t)row * 1024 + cc;
                    if (sel == 0) o0[idx] = v;
                    else if (sel == 1) o1[idx] = v;
                    else if (sel == 2) o2[idx] = v;
                    else o3[idx] = sigm(v + aux[cc]);
                } else {
                    size_t idx = (size_t)row * N + col;
                    o0[idx] = aux[idx] + v;
                }
            }
        }
    }
}

// ---------------- plain bf16 MFMA GEMM, sparse-expert-aware --------------------
// meta layout (ints): [0..7]=cnt, [8..15]=off, [16..23]=cnt2 (gather cursors)
enum { EP_TANHB = 0, EP_BF16 = 1, EP_MOE = 2, EP_MOEM = 3, EP_FFN1 = 4, EP_KV = 5 };

template <int EP>
__global__ __launch_bounds__(256) void bgemm_kernel(
    const __hip_bfloat16* __restrict__ A, const __hip_bfloat16* __restrict__ Bt,
    void* __restrict__ Cv, void* __restrict__ Cv2, int M, int N, int K,
    const int* __restrict__ meta, int e,
    const int* __restrict__ tokidx, const float* __restrict__ tokgate,
    const float* __restrict__ aux2) {
    int rows = M;
    int offA = 0;
    const int* sidx = nullptr;
    const float* sgate = nullptr;
    if (meta) {
        if (EP == EP_TANHB) {
            rows = meta[6] + meta[7];
        } else if (EP == EP_KV) {
            rows = meta[e] * 4;
            offA = (meta[8 + e] - meta[14]) * 4;
        } else {
            rows = meta[e];
            if (EP == EP_MOE || EP == EP_MOEM) {
                sidx = tokidx + meta[8 + e];
                sgate = tokgate + meta[8 + e];
            } else {
                offA = meta[8 + e];
            }
        }
    }
    int m0 = blockIdx.y * 128;
    if (m0 >= rows) return;

    __shared__ __align__(16) __hip_bfloat16 Asm[8192];
    __shared__ __align__(16) __hip_bfloat16 Bsm[8192];
    int tid = threadIdx.x;
    int n0 = blockIdx.x * 128;
    int l = tid & 63, wv = tid >> 6;
    int wm = (wv >> 1) * 64, wn = (wv & 1) * 64;
    int lr = l & 15, lq = l >> 4;

    f32x4 acc[4][4];
#pragma unroll
    for (int i = 0; i < 4; i++)
#pragma unroll
        for (int j = 0; j < 4; j++) acc[i][j] = (f32x4){0.f, 0.f, 0.f, 0.f};

    int srow = tid >> 3;
    int sq = (tid & 7) ^ (srow & 7);
    size_t arow = (size_t)(m0 + offA + srow) * K + (sq << 3);
    size_t brow = (size_t)(n0 + srow) * K + (sq << 3);

    int ks = K / gridDim.z;
    int kbeg = blockIdx.z * ks, kend = kbeg + ks;

    for (int kt = kbeg; kt < kend; kt += 64) {
#pragma unroll
        for (int c = 0; c < 4; c++) {
            size_t go = (size_t)(c * 32) * K + kt;
            gl_lds16(A + arow + go, Asm + c * 2048 + tid * 8);
            gl_lds16(Bt + brow + go, Bsm + c * 2048 + tid * 8);
        }
        __syncthreads();
#pragma unroll
        for (int kc = 0; kc < 64; kc += 32) {
            bfrag af[4], bf[4];
#pragma unroll
            for (int mi = 0; mi < 4; mi++) {
                int rr = wm + mi * 16 + lr;
                af[mi] = *(const bfrag*)&Asm[rr * 64 + ((((kc >> 3) + lq) ^ (rr & 7)) << 3)];
            }
#pragma unroll
            for (int ni = 0; ni < 4; ni++) {
                int rr = wn + ni * 16 + lr;
                bf[ni] = *(const bfrag*)&Bsm[rr * 64 + ((((kc >> 3) + lq) ^ (rr & 7)) << 3)];
            }
#pragma unroll
            for (int mi = 0; mi < 4; mi++)
#pragma unroll
                for (int ni = 0; ni < 4; ni++)
                    acc[mi][ni] = __builtin_amdgcn_mfma_f32_16x16x32_bf16(
                        af[mi], bf[ni], acc[mi][ni], 0, 0, 0);
        }
        __syncthreads();
    }

    float* Cf = (float*)Cv;
    __hip_bfloat16* Cb = (__hip_bfloat16*)Cv;
#pragma unroll
    for (int mi = 0; mi < 4; mi++) {
#pragma unroll
        for (int r = 0; r < 4; r++) {
            int row = m0 + wm + mi * 16 + lq * 4 + r;
            if (row >= rows) continue;
            int t = 0; float g = 0.f;
            if (EP == EP_MOE || EP == EP_MOEM) { t = sidx[row]; g = sgate[row]; }
#pragma unroll
            for (int ni = 0; ni < 4; ni++) {
                int col = n0 + wn + ni * 16 + lr;
                float v = acc[mi][ni][r];
                if (EP == EP_TANHB) {
                    Cb[(size_t)row * N + col] = __float2bfloat16(tanhf(v));
                } else if (EP == EP_BF16) {
                    Cb[(size_t)row * N + col] = __float2bfloat16(v);
                } else if (EP == EP_MOE) {
                    float* p = Cf + (size_t)t * 1024 + col;
                    *p = *p + g * v;
                } else if (EP == EP_MOEM) {
                    atomicAdd(Cf + (size_t)t * 1024 + col,
                              g * aux2[(size_t)row * 1024 + col] * v);
                } else if (EP == EP_FFN1) {
                    if ((col >> 10) == 0) {
                        Cf[(size_t)row * 1024 + col] = sigm(v);
                    } else {
                        float q = fmaxf(v, 0.f);
                        ((__hip_bfloat16*)Cv2)[(size_t)row * 4096 + col - 1024] =
                            __float2bfloat16(q * q);
                    }
                } else if (EP == EP_KV) {
                    if ((col >> 10) == 0)
                        Cb[(size_t)row * 1024 + col] = __float2bfloat16(v);
                    else
                        ((__hip_bfloat16*)Cv2)[(size_t)row * 1024 + col - 1024] =
                            __float2bfloat16(v);
                }
            }
        }
    }
}

// ---------------- chunked RWKV scan (3 passes) ----------------
__global__ __launch_bounds__(256) void scan_pass1(
    const float* __restrict__ k, const float* __restrict__ v,
    const float* __restrict__ w, float* __restrict__ Mbuf,
    float* __restrict__ Pbuf) {
    int c = blockIdx.x, bh = blockIdx.y;
    int b = bh >> 4, h = bh & 15;
    int tid = threadIdx.x, j = tid & 63, ig = tid >> 6;
    __shared__ float sbuf[2][3][64];
    float S[16], P[16];
#pragma unroll
    for (int ii = 0; ii < 16; ii++) { S[ii] = 0.f; P[ii] = 1.f; }

    size_t base = ((size_t)b * Tn + (size_t)c * CHL) * Cdim + (size_t)h * HSn + j;
    const float* srcs[3] = {k, v, w};
    const float* myp = (ig > 0) ? srcs[ig - 1] + base : k + base;

    const int CH = 8;
    float buf[CH];
#pragma unroll
    for (int u = 0; u < CH; u++) buf[u] = (ig > 0) ? myp[(size_t)u * Cdim] : 0.f;

    for (int tc = 0; tc < CHL; tc += CH) {
        float nbuf[CH];
#pragma unroll
        for (int u = 0; u < CH; u++) {
            int t2 = tc + CH + u;
            nbuf[u] = (ig > 0 && t2 < CHL) ? myp[(size_t)t2 * Cdim] : 0.f;
        }
#pragma unroll
        for (int u = 0; u < CH; u++) {
            int p = (tc + u) & 1;
            if (ig > 0) sbuf[p][ig - 1][j] = buf[u];
            __syncthreads();
            float vj = sbuf[p][1][j];
            const float* skp = sbuf[p][0];
            const float* swp = sbuf[p][2];
#pragma unroll
            for (int ii = 0; ii < 16; ii++) {
                int i = (ig << 4) + ii;
                float wi = swp[i];
                S[ii] = S[ii] * wi + skp[i] * vj;
                P[ii] *= wi;
            }
        }
#pragma unroll
        for (int u = 0; u < CH; u++) buf[u] = nbuf[u];
    }
    size_t mo = ((size_t)c * 32 + bh) * 4096;
#pragma unroll
    for (int ii = 0; ii < 16; ii++)
        Mbuf[mo + (size_t)((ig << 4) + ii) * 64 + j] = S[ii];
    if (j == 0) {
#pragma unroll
        for (int ii = 0; ii < 16; ii++)
            Pbuf[((size_t)c * 32 + bh) * 64 + (ig << 4) + ii] = P[ii];
    }
}

__global__ __launch_bounds__(256) void scan_pass2(
    const float* __restrict__ Mbuf, const float* __restrict__ Pbuf,
    float* __restrict__ Sinb) {
    int bh = blockIdx.y;
    int idx = blockIdx.x * 256 + threadIdx.x;
    int i = idx >> 6;
    float S = 0.f;
    for (int c = 0; c < NCH; c++) {
        size_t o = ((size_t)c * 32 + bh);
        Sinb[o * 4096 + idx] = S;
        S = Pbuf[o * 64 + i] * S + Mbuf[o * 4096 + idx];
    }
}

__global__ __launch_bounds__(256) void scan_pass3(
    const float* __restrict__ r, const float* __restrict__ k,
    const float* __restrict__ v, const float* __restrict__ w,
    const float* __restrict__ Sinb,
    __hip_bfloat16* __restrict__ sh, __hip_bfloat16* __restrict__ sl) {
    int c = blockIdx.x, bh = blockIdx.y;
    int b = bh >> 4, h = bh & 15;
    int tid = threadIdx.x, j = tid & 63, ig = tid >> 6;
    __shared__ float sbuf[2][4][64];
    __shared__ float red[2][4][64];
    float S[16];
    size_t so = ((size_t)c * 32 + bh) * 4096;
#pragma unroll
    for (int ii = 0; ii < 16; ii++)
        S[ii] = Sinb[so + (size_t)((ig << 4) + ii) * 64 + j];

    size_t base = ((size_t)b * Tn + (size_t)c * CHL) * Cdim + (size_t)h * HSn + j;
    const float* srcs[4] = {r, k, v, w};
    const float* myp = srcs[ig] + base;

    const int CH = 8;
    float buf[CH];
#pragma unroll
    for (int u = 0; u < CH; u++) buf[u] = myp[(size_t)u * Cdim];
    float part_prev = 0.f;

    for (int tc = 0; tc < CHL; tc += CH) {
        float nbuf[CH];
#pragma unroll
        for (int u = 0; u < CH; u++) {
            int t2 = tc + CH + u;
            nbuf[u] = (t2 < CHL) ? myp[(size_t)t2 * Cdim] : 0.f;
        }
#pragma unroll
        for (int u = 0; u < CH; u++) {
            int t = tc + u;
            int p = t & 1;
            sbuf[p][ig][j] = buf[u];
            red[p][ig][j] = part_prev;
            __syncthreads();
            if (ig == 0 && t > 0) {
                float val = red[p][0][j] + red[p][1][j] + red[p][2][j] + red[p][3][j];
                __hip_bfloat16 hi = __float2bfloat16(val);
                size_t pos = base + (size_t)(t - 1) * Cdim;
                sh[pos] = hi;
                sl[pos] = __float2bfloat16(val - __bfloat162float(hi));
            }
            float vj = sbuf[p][2][j];
            const float* srp = sbuf[p][0];
            const float* skp = sbuf[p][1];
            const float* swp = sbuf[p][3];
            float part = 0.f;
#pragma unroll
            for (int ii = 0; ii < 16; ii++) {
                int i = (ig << 4) + ii;
                S[ii] = S[ii] * swp[i] + skp[i] * vj;
                part += srp[i] * S[ii];
            }
            part_prev = part;
        }
#pragma unroll
        for (int u = 0; u < CH; u++) buf[u] = nbuf[u];
    }
    red[0][ig][j] = part_prev;
    __syncthreads();
    if (ig == 0) {
        float val = red[0][0][j] + red[0][1][j] + red[0][2][j] + red[0][3][j];
        __hip_bfloat16 hi = __float2bfloat16(val);
        size_t pos = base + (size_t)(CHL - 1) * Cdim;
        sh[pos] = hi;
        sl[pos] = __float2bfloat16(val - __bfloat162float(hi));
    }
}

// ---------------- Routing: winners + gates + per-expert counts ----------------
__global__ __launch_bounds__(256) void routing_kernel(
    const float* __restrict__ h, const float* __restrict__ conf_w,
    const float* __restrict__ conf_b, const float* __restrict__ Wa,
    const float* __restrict__ ba, const float* __restrict__ cap,
    int* __restrict__ meta, int2* __restrict__ winfo, float2* __restrict__ gvals) {
    int row = blockIdx.x;
    const float* hr = h + (size_t)row * Cdim;
    float pc[8], pa[8];
#pragma unroll
    for (int e = 0; e < 8; e++) { pc[e] = 0.f; pa[e] = 0.f; }
    for (int c = threadIdx.x; c < Cdim; c += 256) {
        float hv = hr[c];
#pragma unroll
        for (int e = 0; e < 8; e++) {
            pc[e] += hv * conf_w[(size_t)e * Cdim + c];
            pa[e] += hv * Wa[(size_t)c * En + e];
        }
    }
    __shared__ float red[256];
    __shared__ float vals[16];
    for (int e = 0; e < 16; e++) {
        red[threadIdx.x] = (e < 8) ? pc[e] : pa[e - 8];
        __syncthreads();
        for (int st = 128; st > 0; st >>= 1) {
            if (threadIdx.x < st) red[threadIdx.x] += red[threadIdx.x + st];
            __syncthreads();
        }
        if (threadIdx.x == 0) vals[e] = red[0];
        __syncthreads();
    }
    if (threadIdx.x == 0) {
        float conf[8], aff[8];
        for (int e = 0; e < 8; e++) {
            conf[e] = sigm(vals[e] + conf_b[e]);
            aff[e]  = vals[8 + e] + ba[e];
        }
        float mx = aff[0];
        for (int e = 1; e < 8; e++) mx = fmaxf(mx, aff[e]);
        float se = 0.f, ex[8];
        for (int e = 0; e < 8; e++) { ex[e] = expf(aff[e] - mx); se += ex[e]; }
        float bids[8];
        for (int e = 0; e < 8; e++) bids[e] = conf[e] * cap[e] + ex[e] / se;
        int w0 = 0;
        for (int e = 1; e < 8; e++) if (bids[e] > bids[w0]) w0 = e;
        int w1 = -1;
        for (int e = 0; e < 8; e++) {
            if (e == w0) continue;
            if (w1 < 0 || bids[e] > bids[w1]) w1 = e;
        }
        float e1 = expf(bids[w1] - bids[w0]);
        float g0 = 1.f / (1.f + e1);
        float g1 = e1 / (1.f + e1);
        winfo[row] = make_int2(w0, w1);
        gvals[row] = make_float2(g0, g1);
        atomicAdd(&meta[w0], 1);
        atomicAdd(&meta[w1], 1);
    }
}

// ---------------- offsets: exclusive scan of counts ----------------
__global__ void offsets_kernel(int* __restrict__ meta) {
    if (threadIdx.x == 0 && blockIdx.x == 0) {
        int acc = 0;
        for (int e = 0; e < 8; e++) { meta[8 + e] = acc; acc += meta[e]; }
    }
}

// ---------------- assign positions + gather compact activations ---------------
__global__ __launch_bounds__(256) void gather_kernel(
    const __hip_bfloat16* __restrict__ h_bf, const __hip_bfloat16* __restrict__ st,
    const int2* __restrict__ winfo, const float2* __restrict__ gvals,
    int* __restrict__ meta, int* __restrict__ tokidx, float* __restrict__ tokgate,
    __hip_bfloat16* __restrict__ hc, __hip_bfloat16* __restrict__ hsc) {
    int t = blockIdx.x;
    int tid = threadIdx.x;
    __shared__ int spos[2], sw[2];
    if (tid == 0) {
        int2 w = winfo[t];
        float2 g = gvals[t];
#pragma unroll
        for (int s = 0; s < 2; s++) {
            int e = s ? w.y : w.x;
            int p = meta[8 + e] + atomicAdd(&meta[16 + e], 1);
            tokidx[p] = t;
            tokgate[p] = s ? g.y : g.x;
            spos[s] = p; sw[s] = e;
        }
    }
    __syncthreads();
    const ushort4* hrow = (const ushort4*)(h_bf + (size_t)t * 1024);
    ushort4 hv = hrow[tid];
    int off6 = meta[14];
#pragma unroll
    for (int s = 0; s < 2; s++) {
        int p = spos[s];
        ((ushort4*)(hc + (size_t)p * 1024))[tid] = hv;
        if (sw[s] >= 6) {
            int lp = p - off6;
            ((ushort4*)(hsc + (size_t)lp * 2048))[tid] = hv;
            ((ushort4*)(hsc + (size_t)lp * 2048 + 1024))[tid] =
                ((const ushort4*)(st + (size_t)t * 1024))[tid];
        }
    }
}

// ---------------- transformer-expert prefix attention (compact) ----------------
__global__ __launch_bounds__(256) void tr_attn_kernel(
    const __hip_bfloat16* __restrict__ qc, const __hip_bfloat16* __restrict__ kpc,
    const __hip_bfloat16* __restrict__ vpc, __hip_bfloat16* __restrict__ attnc,
    const int* __restrict__ meta, int e) {
    int cnt = meta[e];
    int idx = blockIdx.x * 4 + (threadIdx.x >> 6);   // local_row * 16 + head
    int lane = threadIdx.x & 63;
    int n = idx >> 4, h = idx & 15;
    if (n >= cnt) return;
    float qd = __bfloat162float(qc[(size_t)n * Cdim + (size_t)h * HSn + lane]);
    float s[4];
#pragma unroll
    for (int p = 0; p < 4; p++) {
        float t = qd * __bfloat162float(kpc[((size_t)n * Pn + p) * Cdim + (size_t)h * HSn + lane]);
        for (int off = 32; off > 0; off >>= 1) t += __shfl_down(t, off);
        s[p] = __shfl(t, 0);
    }
    const float scale = 0.125f;
    float mx = fmaxf(fmaxf(s[0], s[1]), fmaxf(s[2], s[3])) * scale;
    float es = 0.f, a[4];
#pragma unroll
    for (int p = 0; p < 4; p++) { a[p] = expf(s[p] * scale - mx); es += a[p]; }
    float o = 0.f;
#pragma unroll
    for (int p = 0; p < 4; p++)
        o += (a[p] / es) * __bfloat162float(vpc[((size_t)n * Pn + p) * Cdim + (size_t)h * HSn + lane]);
    attnc[(size_t)n * Cdim + (size_t)h * HSn + lane] = __float2bfloat16(o);
}

// ---------------- orchestration ----------------
extern "C" void kernel_launch(void* const* d_in, const int* in_sizes, int n_in,
                              void* d_out, int out_size, void* d_ws, size_t ws_size,
                              hipStream_t stream) {
    const float* x      = (const float*)d_in[0];
    const float* cap    = (const float*)d_in[2];
    const float* ln1_w  = (const float*)d_in[3];
    const float* ln1_b  = (const float*)d_in[4];
    const float* ln2_w  = (const float*)d_in[5];
    const float* ln2_b  = (const float*)d_in[6];
    const float* Wr     = (const float*)d_in[7];
    const float* Wk     = (const float*)d_in[8];
    const float* Wv     = (const float*)d_in[9];
    const float* Ww     = (const float*)d_in[10];
    const float* w_bias = (const float*)d_in[11];
    const float* Wo     = (const float*)d_in[12];
    const float* conf_w = (const float*)d_in[13];
    const float* conf_b = (const float*)d_in[14];
    const float* Wa     = (const float*)d_in[17];
    const float* ba     = (const float*)d_in[18];
    const float* Wb     = (const float*)d_in[19];
    const float* ffn_Wr = (const float*)d_in[20];
    const float* ffn_Wk = (const float*)d_in[21];
    const float* ffn_Wv = (const float*)d_in[22];
    const float* tr_Wq  = (const float*)d_in[23];
    const float* tr_Wk  = (const float*)d_in[24];
    const float* tr_Wv  = (const float*)d_in[25];
    const float* tr_Wo  = (const float*)d_in[26];

    float* xout  = (float*)d_out;
    float* vflat = (float*)d_out + (size_t)BTn * Cdim;

    char* ws = (char*)d_ws;
    const size_t MB = 1ull << 20;
    // attention phase
    __hip_bfloat16* xln_hi  = (__hip_bfloat16*)(ws + 0 * MB);
    __hip_bfloat16* xln_lo  = (__hip_bfloat16*)(ws + 8 * MB);
    __hip_bfloat16* Wall_hi = (__hip_bfloat16*)(ws + 16 * MB);
    __hip_bfloat16* Wall_lo = (__hip_bfloat16*)(ws + 24 * MB);
    float*          rbuf    = (float*)(ws + 32 * MB);
    float*          kbuf    = (float*)(ws + 48 * MB);
    float*          wbuf    = (float*)(ws + 64 * MB);
    float*          Pbuf    = (float*)(ws + 80 * MB);
    __hip_bfloat16* Wo_hi   = (__hip_bfloat16*)(ws + 81 * MB);
    __hip_bfloat16* Wo_lo   = (__hip_bfloat16*)(ws + 83 * MB);
    float*          Mbuf    = (float*)(ws + 0 * MB);    // over xln (dead)
    float*          Sinb    = (float*)(ws + 8 * MB);
    __hip_bfloat16* st_hi   = (__hip_bfloat16*)(ws + 16 * MB);  // over Wall (dead)
    __hip_bfloat16* st_lo   = (__hip_bfloat16*)(ws + 24 * MB);
    float*          hbuf    = (float*)(ws + 32 * MB);   // over rbuf (dead)
    __hip_bfloat16* h_bf    = (__hip_bfloat16*)(ws + 48 * MB);  // over kbuf (dead)
    // compact expert structures
    __hip_bfloat16* hc      = (__hip_bfloat16*)(ws + 56 * MB);  // 8320 rows, 56-74
    __hip_bfloat16* hsc     = (__hip_bfloat16*)(ws + 74 * MB);  // 8320x2048, 74-108
    __hip_bfloat16* Wt_b    = (__hip_bfloat16*)(ws + 108 * MB); // 16MB, 108-124
    __hip_bfloat16* prefixc = (__hip_bfloat16*)(ws + 124 * MB); // 68MB, 124-192
    // FFN phase (hsc/Wt_b dead after prefix GEMM)
    __hip_bfloat16* eWall   = (__hip_bfloat16*)(ws + 0 * MB);   // 10MB
    __hip_bfloat16* eWv_t   = (__hip_bfloat16*)(ws + 10 * MB);  // 8MB
    float*          rg      = (float*)(ws + 18 * MB);           // 17MB, 18-35
    __hip_bfloat16* kk      = (__hip_bfloat16*)(ws + 74 * MB);  // 35MB, 74-109
    // TR phase (FFN temporaries dead)
    __hip_bfloat16* vpc     = (__hip_bfloat16*)(ws + 0 * MB);   // 34MB
    __hip_bfloat16* tkv     = (__hip_bfloat16*)(ws + 34 * MB);  // 4MB
    __hip_bfloat16* tq      = (__hip_bfloat16*)(ws + 38 * MB);  // 2MB
    __hip_bfloat16* to_     = (__hip_bfloat16*)(ws + 40 * MB);  // 2MB
    __hip_bfloat16* qc      = (__hip_bfloat16*)(ws + 42 * MB);  // 9MB
    __hip_bfloat16* attnc   = (__hip_bfloat16*)(ws + 74 * MB);  // 9MB
    __hip_bfloat16* kpc     = (__hip_bfloat16*)(ws + 83 * MB);  // 34MB, 83-117
    // routing metadata
    int*    meta    = (int*)(ws + 200 * MB);                    // [cnt8|off8|cnt2_8]
    int*    tokidx  = (int*)(ws + 200 * MB + (64 << 10));
    float*  tokgate = (float*)(ws + 200 * MB + (128 << 10));
    int2*   winfo   = (int2*)(ws + 200 * MB + (192 << 10));
    float2* gvals   = (float2*)(ws + 200 * MB + (256 << 10));
    (void)ws_size; (void)in_sizes; (void)n_in; (void)out_size;

    dim3 blk(256);
    dim3 tblk(32, 8);
    auto grid  = [](int M, int N) { return dim3(N / 128, M / 128); };
    auto tgrid = [](int K, int N) { return dim3(N / 32, K / 32); };
    const size_t CC = (size_t)Cdim * Cdim;

    // 0. weight conversions + meta zero
    hipMemsetAsync(meta, 0, 96, stream);
    convT_split_kernel<<<tgrid(Cdim, Cdim), tblk, 0, stream>>>(Wr, Wall_hi, Wall_lo, Cdim, Cdim);
    convT_split_kernel<<<tgrid(Cdim, Cdim), tblk, 0, stream>>>(Wk, Wall_hi + CC, Wall_lo + CC, Cdim, Cdim);
    convT_split_kernel<<<tgrid(Cdim, Cdim), tblk, 0, stream>>>(Wv, Wall_hi + 2 * CC, Wall_lo + 2 * CC, Cdim, Cdim);
    convT_split_kernel<<<tgrid(Cdim, Cdim), tblk, 0, stream>>>(Ww, Wall_hi + 3 * CC, Wall_lo + 3 * CC, Cdim, Cdim);
    convT_split_kernel<<<tgrid(Cdim, Cdim), tblk, 0, stream>>>(Wo, Wo_hi, Wo_lo, Cdim, Cdim);
    convT_kernel<<<tgrid(2 * Cdim, Pn * Cdim), tblk, 0, stream>>>(Wb, Wt_b, 2 * Cdim, Pn * Cdim);

    // 1. ln1 -> hi/lo
    ln_kernel<<<BTn, blk, 0, stream>>>(x, ln1_w, ln1_b, nullptr, xln_hi, xln_lo);
    // 2. fused r/k/v/w projections (bf16x3)
    bgemm3_kernel<EP3_QKVW><<<grid(BTn, 4 * Cdim), blk, 0, stream>>>(
        xln_hi, xln_lo, Wall_hi, Wall_lo, rbuf, kbuf, vflat, wbuf, BTn, 4 * Cdim, Cdim, w_bias);
    // 3. chunked scan
    scan_pass1<<<dim3(NCH, 32), blk, 0, stream>>>(kbuf, vflat, wbuf, Mbuf, Pbuf);
    scan_pass2<<<dim3(16, 32), blk, 0, stream>>>(Mbuf, Pbuf, Sinb);
    scan_pass3<<<dim3(NCH, 32), blk, 0, stream>>>(rbuf, kbuf, vflat, wbuf, Sinb, st_hi, st_lo);
    // 4. x_after_att = x + state @ Wo
    bgemm3_kernel<EP3_ADD><<<grid(BTn, Cdim), blk, 0, stream>>>(
        st_hi, st_lo, Wo_hi, Wo_lo, xout, nullptr, nullptr, nullptr, BTn, Cdim, Cdim, x);
    // 5. ln2
    ln_kernel<<<BTn, blk, 0, stream>>>(xout, ln2_w, ln2_b, hbuf, h_bf, nullptr);
    // 6. routing -> winners/gates/counts
    routing_kernel<<<BTn, blk, 0, stream>>>(hbuf, conf_w, conf_b, Wa, ba, cap, meta, winfo, gvals);
    offsets_kernel<<<1, 64, 0, stream>>>(meta);
    // 7. gather compact activations (hc for all, hsc for TR winners)
    gather_kernel<<<BTn, blk, 0, stream>>>(h_bf, st_hi, winfo, gvals, meta, tokidx, tokgate, hc, hsc);
    // 8. sparse bridge prefix = tanh(hsc @ Wb) over TR rows only
    bgemm_kernel<EP_TANHB><<<grid(2 * BTn, Pn * Cdim), blk, 0, stream>>>(
        hsc, Wt_b, prefixc, nullptr, 2 * BTn, Pn * Cdim, 2 * Cdim, meta, 0, nullptr, nullptr, nullptr);
    // 9. FFN experts (sparse)
    for (int e = 0; e < NRn; e++) {
        convT_kernel<<<tgrid(Cdim, Cdim), tblk, 0, stream>>>(ffn_Wr + (size_t)e * CC, eWall, Cdim, Cdim);
        convT_kernel<<<tgrid(Cdim, FFn), tblk, 0, stream>>>(ffn_Wk + (size_t)e * Cdim * FFn, eWall + CC, Cdim, FFn);
        convT_kernel<<<tgrid(FFn, Cdim), tblk, 0, stream>>>(ffn_Wv + (size_t)e * FFn * Cdim, eWv_t, FFn, Cdim);
        bgemm_kernel<EP_FFN1><<<grid(BTn, 5 * Cdim), blk, 0, stream>>>(
            hc, eWall, rg, kk, BTn, 5 * Cdim, Cdim, meta, e, nullptr, nullptr, nullptr);
        bgemm_kernel<EP_MOEM><<<dim3(Cdim / 128, BTn / 128, 2), blk, 0, stream>>>(
            kk, eWv_t, xout, nullptr, BTn, Cdim, FFn, meta, e, tokidx, tokgate, rg);
    }
    // 10. transformer experts (sparse)
    for (int t = 0; t < NTn; t++) {
        int e = NRn + t;
        convT_kernel<<<tgrid(Cdim, Cdim), tblk, 0, stream>>>(tr_Wk + (size_t)t * CC, tkv, Cdim, Cdim);
        convT_kernel<<<tgrid(Cdim, Cdim), tblk, 0, stream>>>(tr_Wv + (size_t)t * CC, tkv + CC, Cdim, Cdim);
        convT_kernel<<<tgrid(Cdim, Cdim), tblk, 0, stream>>>(tr_Wq + (size_t)t * CC, tq, Cdim, Cdim);
        convT_kernel<<<tgrid(Cdim, Cdim), tblk, 0, stream>>>(tr_Wo + (size_t)t * CC, to_, Cdim, Cdim);
        bgemm_kernel<EP_KV><<<grid(4 * BTn, 2 * Cdim), blk, 0, stream>>>(
            prefixc, tkv, kpc, vpc, 4 * BTn, 2 * Cdim, Cdim, meta, e, nullptr, nullptr, nullptr);
        bgemm_kernel<EP_BF16><<<grid(BTn, Cdim), blk, 0, stream>>>(
            hc, tq, qc, nullptr, BTn, Cdim, Cdim, meta, e, nullptr, nullptr, nullptr);
        tr_attn_kernel<<<(BTn * Hn) / 4, blk, 0, stream>>>(qc, kpc, vpc, attnc, meta, e);
        bgemm_kernel<EP_MOE><<<grid(BTn, Cdim), blk, 0, stream>>>(
            attnc, to_, xout, nullptr, BTn, Cdim, Cdim, meta, e, tokidx, tokgate, nullptr);
    }
}